// Round 1
// baseline (1233.396 us; speedup 1.0000x reference)
//
#include <hip/hip_runtime.h>

#define DEVINL __device__ __forceinline__

// Order-preserving float->uint encoding for atomicMax on floats.
// enc(0) is reserved: 0 is below every encoded float (sentinel = "no edge").
DEVINL unsigned enc_f(float f) {
    unsigned u = __float_as_uint(f);
    return (u & 0x80000000u) ? ~u : (u | 0x80000000u);
}
DEVINL float dec_f(unsigned e) {
    unsigned u = (e & 0x80000000u) ? (e ^ 0x80000000u) : ~e;
    return __uint_as_float(u);
}

// ---------------- shared GEMM tile compute ----------------
// C tile: 64 nodes x 128 cols, 256 threads, thread = (rg, cg): 8 rows x 4 cols.
// At padded to 65 floats/row: row stride 65*4B -> rg-groups hit distinct banks
// (2-way aliasing only, which is free on gfx950).
DEVINL void mm_tile(const float (*Wt)[128], const float (*At)[65],
                    float4 acc[8], int rg, int cg) {
#pragma unroll 8
    for (int j = 0; j < 64; ++j) {
        float4 w = *(const float4*)&Wt[j][cg * 4];
#pragma unroll
        for (int r = 0; r < 8; ++r) {
            float a = At[rg * 8 + r][j];
            acc[r].x = fmaf(a, w.x, acc[r].x);
            acc[r].y = fmaf(a, w.y, acc[r].y);
            acc[r].z = fmaf(a, w.z, acc[r].z);
            acc[r].w = fmaf(a, w.w, acc[r].w);
        }
    }
}

// z = relu([x, pre_h] @ W_enc + b_enc)   (W_enc row 0 = x weights)
__global__ __launch_bounds__(256) void k_enc(
    const float* __restrict__ x, const float* __restrict__ preh,
    const float* __restrict__ Wenc, const float* __restrict__ benc,
    float* __restrict__ z, int N)
{
    __shared__ float Wt[64][128];
    __shared__ float At[64][65];
    __shared__ float xs[64];
    __shared__ float w0s[128];
    __shared__ float bs[128];
    int t = threadIdx.x;
    int n0 = blockIdx.x * 64;
    if (t < 64) xs[t] = (n0 + t < N) ? x[n0 + t] : 0.f;
    if (t < 128) { w0s[t] = Wenc[t]; bs[t] = benc[t]; }
    __syncthreads();
    int rg = t >> 5, cg = t & 31;
    float4 w0 = *(const float4*)&w0s[cg * 4];
    float4 acc[8];
#pragma unroll
    for (int r = 0; r < 8; ++r) {
        float xv = xs[rg * 8 + r];
        acc[r] = make_float4(xv * w0.x, xv * w0.y, xv * w0.z, xv * w0.w);
    }
    for (int kk = 0; kk < 128; kk += 64) {
        __syncthreads();
        for (int i = t; i < 64 * 128; i += 256) {
            int r = i >> 7, c = i & 127;
            Wt[r][c] = Wenc[128 + (kk + r) * 128 + c];  // rows 1..128
        }
        for (int i = t; i < 64 * 64; i += 256) {
            int r = i >> 6, c = i & 63;
            int n = n0 + r;
            At[r][c] = (n < N) ? preh[(size_t)n * 128 + kk + c] : 0.f;
        }
        __syncthreads();
        mm_tile(Wt, At, acc, rg, cg);
    }
    int colb = cg * 4;
#pragma unroll
    for (int r = 0; r < 8; ++r) {
        int n = n0 + rg * 8 + r;
        if (n < N) {
            float4 v;
            v.x = fmaxf(acc[r].x + bs[colb + 0], 0.f);
            v.y = fmaxf(acc[r].y + bs[colb + 1], 0.f);
            v.z = fmaxf(acc[r].z + bs[colb + 2], 0.f);
            v.w = fmaxf(acc[r].w + bs[colb + 3], 0.f);
            *(float4*)&z[(size_t)n * 128 + colb] = v;
        }
    }
}

// P = z @ W_M[0:128,:]  (blockIdx.y==0),  Q = z @ W_M[128:256,:] (blockIdx.y==1)
__global__ __launch_bounds__(256) void k_pq(
    const float* __restrict__ z, const float* __restrict__ WM,
    float* __restrict__ P, float* __restrict__ Q, int N)
{
    __shared__ float Wt[64][128];
    __shared__ float At[64][65];
    int t = threadIdx.x;
    int n0 = blockIdx.x * 64;
    const float* W = (blockIdx.y == 0) ? WM : WM + 128 * 128;
    float* C = (blockIdx.y == 0) ? P : Q;
    int rg = t >> 5, cg = t & 31;
    float4 acc[8];
#pragma unroll
    for (int r = 0; r < 8; ++r) acc[r] = make_float4(0.f, 0.f, 0.f, 0.f);
    for (int kk = 0; kk < 128; kk += 64) {
        __syncthreads();
        for (int i = t; i < 64 * 128; i += 256) {
            int r = i >> 7, c = i & 127;
            Wt[r][c] = W[(kk + r) * 128 + c];
        }
        for (int i = t; i < 64 * 64; i += 256) {
            int r = i >> 6, c = i & 63;
            int n = n0 + r;
            At[r][c] = (n < N) ? z[(size_t)n * 128 + kk + c] : 0.f;
        }
        __syncthreads();
        mm_tile(Wt, At, acc, rg, cg);
    }
    int colb = cg * 4;
#pragma unroll
    for (int r = 0; r < 8; ++r) {
        int n = n0 + rg * 8 + r;
        if (n < N) *(float4*)&C[(size_t)n * 128 + colb] = acc[r];
    }
}

// Per-edge: atomicMax of enc(Q[src,k] + attr*w3[k]) into Menc[dst,k]
__global__ __launch_bounds__(256) void k_edge(
    const int* __restrict__ ei, const float* __restrict__ attr,
    const float* __restrict__ Q, const float* __restrict__ w3,
    unsigned* __restrict__ Menc, int E)
{
    int gid = blockIdx.x * blockDim.x + threadIdx.x;
    int e = gid >> 5;
    if (e >= E) return;
    int lane = gid & 31;
    int src = ei[e];
    int dst = ei[E + e];
    float a = attr[e];
    float4 q = ((const float4*)(Q + (size_t)src * 128))[lane];
    float4 w = ((const float4*)w3)[lane];
    unsigned* M = Menc + (size_t)dst * 128 + lane * 4;
    atomicMax(M + 0, enc_f(fmaf(a, w.x, q.x)));
    atomicMax(M + 1, enc_f(fmaf(a, w.y, q.y)));
    atomicMax(M + 2, enc_f(fmaf(a, w.z, q.z)));
    atomicMax(M + 3, enc_f(fmaf(a, w.w, q.w)));
}

// h = relu(z @ WU[0:128] + agg @ WU[128:256] + bU),
// agg reconstructed elementwise: max(0, P + b_M + decode(Menc)), sentinel->0
__global__ __launch_bounds__(256) void k_h(
    const float* __restrict__ z, const float* __restrict__ P,
    const unsigned* __restrict__ Menc, const float* __restrict__ bM,
    const float* __restrict__ WU, const float* __restrict__ bU,
    float* __restrict__ h, int N)
{
    __shared__ float Wt[64][128];
    __shared__ float At[64][65];
    __shared__ float bs[128];
    int t = threadIdx.x;
    int n0 = blockIdx.x * 64;
    if (t < 128) bs[t] = bU[t];
    int rg = t >> 5, cg = t & 31;
    float4 acc[8];
#pragma unroll
    for (int r = 0; r < 8; ++r) acc[r] = make_float4(0.f, 0.f, 0.f, 0.f);
    const float NEG_INF = __uint_as_float(0xff800000u);
    for (int cc = 0; cc < 4; ++cc) {
        int kk = cc * 64;
        __syncthreads();
        for (int i = t; i < 64 * 128; i += 256) {
            int r = i >> 7, c = i & 127;
            Wt[r][c] = WU[(kk + r) * 128 + c];
        }
        if (cc < 2) {
            for (int i = t; i < 64 * 64; i += 256) {
                int r = i >> 6, c = i & 63;
                int n = n0 + r;
                At[r][c] = (n < N) ? z[(size_t)n * 128 + kk + c] : 0.f;
            }
        } else {
            for (int i = t; i < 64 * 64; i += 256) {
                int r = i >> 6, c = i & 63;
                int n = n0 + r;
                float v = 0.f;
                if (n < N) {
                    int ac = kk - 128 + c;
                    unsigned e = Menc[(size_t)n * 128 + ac];
                    float M = e ? dec_f(e) : NEG_INF;
                    v = fmaxf(P[(size_t)n * 128 + ac] + bM[ac] + M, 0.f);
                }
                At[r][c] = v;
            }
        }
        __syncthreads();
        mm_tile(Wt, At, acc, rg, cg);
    }
    int colb = cg * 4;
#pragma unroll
    for (int r = 0; r < 8; ++r) {
        int n = n0 + rg * 8 + r;
        if (n < N) {
            float4 v;
            v.x = fmaxf(acc[r].x + bs[colb + 0], 0.f);
            v.y = fmaxf(acc[r].y + bs[colb + 1], 0.f);
            v.z = fmaxf(acc[r].z + bs[colb + 2], 0.f);
            v.w = fmaxf(acc[r].w + bs[colb + 3], 0.f);
            *(float4*)&h[(size_t)n * 128 + colb] = v;
        }
    }
}

// y[n] = [z[n], h[n]] . W_dec + b_dec — one wave per node (grid-stride)
__global__ __launch_bounds__(256) void k_y(
    const float* __restrict__ z, const float* __restrict__ h,
    const float* __restrict__ Wd, const float* __restrict__ bd,
    float* __restrict__ y, int N)
{
    int tid = blockIdx.x * blockDim.x + threadIdx.x;
    int wid = tid >> 6, lane = tid & 63;
    int nw = (gridDim.x * blockDim.x) >> 6;
    float wz0 = Wd[lane], wz1 = Wd[64 + lane];
    float wh0 = Wd[128 + lane], wh1 = Wd[192 + lane];
    float bb = bd[0];
    for (int n = wid; n < N; n += nw) {
        const float* zr = z + (size_t)n * 128;
        const float* hr = h + (size_t)n * 128;
        float p = zr[lane] * wz0 + zr[64 + lane] * wz1 +
                  hr[lane] * wh0 + hr[64 + lane] * wh1;
#pragma unroll
        for (int o = 32; o > 0; o >>= 1) p += __shfl_down(p, o, 64);
        if (lane == 0) y[n] = p + bb;
    }
}

// column sums of h -> hsum[128]
__global__ __launch_bounds__(256) void k_hsum(
    const float* __restrict__ h, float* __restrict__ hsum, int N)
{
    __shared__ float sd[256];
    int t = threadIdx.x;
    int rows = (N + gridDim.x - 1) / gridDim.x;
    int nstart = blockIdx.x * rows;
    int nend = min(nstart + rows, N);
    int col = t & 127, half = t >> 7;
    float acc = 0.f;
    for (int n = nstart + half; n < nend; n += 2)
        acc += h[(size_t)n * 128 + col];
    sd[t] = acc;
    __syncthreads();
    if (t < 128) atomicAdd(&hsum[t], sd[t] + sd[t + 128]);
}

// tau = (hsum/N) . (W_term[0:128] + W_term[128:256]) + b_term
__global__ __launch_bounds__(128) void k_tau(
    const float* __restrict__ hsum, const float* __restrict__ Wt,
    const float* __restrict__ bt, float* __restrict__ tau, int N)
{
    __shared__ float sd[128];
    int t = threadIdx.x;
    float v = hsum[t] * (1.f / (float)N) * (Wt[t] + Wt[128 + t]);
    sd[t] = v;
    __syncthreads();
    for (int s = 64; s > 0; s >>= 1) {
        if (t < s) sd[t] += sd[t + s];
        __syncthreads();
    }
    if (t == 0) tau[0] = sd[0] + bt[0];
}

extern "C" void kernel_launch(void* const* d_in, const int* in_sizes, int n_in,
                              void* d_out, int out_size, void* d_ws, size_t ws_size,
                              hipStream_t stream)
{
    const float* x     = (const float*)d_in[0];
    const float* preh  = (const float*)d_in[1];
    const int*   ei    = (const int*)d_in[2];
    const float* attr  = (const float*)d_in[3];
    const float* Wenc  = (const float*)d_in[4];
    const float* benc  = (const float*)d_in[5];
    const float* WM    = (const float*)d_in[6];
    const float* bM    = (const float*)d_in[7];
    const float* WU    = (const float*)d_in[8];
    const float* bU    = (const float*)d_in[9];
    const float* Wd    = (const float*)d_in[10];
    const float* bd    = (const float*)d_in[11];
    const float* Wterm = (const float*)d_in[12];
    const float* bterm = (const float*)d_in[13];
    int N = in_sizes[0];
    int E = in_sizes[3];

    float*    z    = (float*)d_ws;
    float*    P    = z + (size_t)N * 128;
    float*    Qb   = P + (size_t)N * 128;
    unsigned* Menc = (unsigned*)(Qb + (size_t)N * 128);
    float*    hsum = (float*)(Menc + (size_t)N * 128);

    float* hout = (float*)d_out;
    float* yout = hout + (size_t)N * 128;
    float* tau  = yout + N;

    int nb = (N + 63) / 64;
    // zero Menc (sentinel) and hsum in one shot (they're contiguous)
    hipMemsetAsync(Menc, 0, ((size_t)N * 128 + 128) * sizeof(unsigned), stream);

    k_enc<<<nb, 256, 0, stream>>>(x, preh, Wenc, benc, z, N);
    k_pq<<<dim3(nb, 2), 256, 0, stream>>>(z, WM, P, Qb, N);
    int eb = (E * 32 + 255) / 256;
    k_edge<<<eb, 256, 0, stream>>>(ei, attr, Qb, WM + 256 * 128, Menc, E);
    k_h<<<nb, 256, 0, stream>>>(z, P, Menc, bM, WU, bU, hout, N);
    k_y<<<256, 256, 0, stream>>>(z, hout, Wd, bd, yout, N);
    k_hsum<<<128, 256, 0, stream>>>(hout, hsum, N);
    k_tau<<<1, 128, 0, stream>>>(hsum, Wterm, bterm, tau, N);
}

// Round 2
// 470.838 us; speedup vs baseline: 2.6196x; 2.6196x over previous
//
#include <hip/hip_runtime.h>

#define DEVINL __device__ __forceinline__

#define BCAP 64  // bucket capacity per node; deg~Poisson(12.8), P(>64)~3e-23

// ---------------- shared GEMM tile compute ----------------
// C tile: 64 nodes x 128 cols, 256 threads, thread = (rg, cg): 8 rows x 4 cols.
// At padded to 65 floats/row (2-way LDS aliasing only, free on gfx950).
DEVINL void mm_tile(const float (*Wt)[128], const float (*At)[65],
                    float4 acc[8], int rg, int cg) {
#pragma unroll 8
    for (int j = 0; j < 64; ++j) {
        float4 w = *(const float4*)&Wt[j][cg * 4];
#pragma unroll
        for (int r = 0; r < 8; ++r) {
            float a = At[rg * 8 + r][j];
            acc[r].x = fmaf(a, w.x, acc[r].x);
            acc[r].y = fmaf(a, w.y, acc[r].y);
            acc[r].z = fmaf(a, w.z, acc[r].z);
            acc[r].w = fmaf(a, w.w, acc[r].w);
        }
    }
}

// z = relu([x, pre_h] @ W_enc + b_enc)   (W_enc row 0 = x weights)
__global__ __launch_bounds__(256) void k_enc(
    const float* __restrict__ x, const float* __restrict__ preh,
    const float* __restrict__ Wenc, const float* __restrict__ benc,
    float* __restrict__ z, int N)
{
    __shared__ float Wt[64][128];
    __shared__ float At[64][65];
    __shared__ float xs[64];
    __shared__ float w0s[128];
    __shared__ float bs[128];
    int t = threadIdx.x;
    int n0 = blockIdx.x * 64;
    if (t < 64) xs[t] = (n0 + t < N) ? x[n0 + t] : 0.f;
    if (t < 128) { w0s[t] = Wenc[t]; bs[t] = benc[t]; }
    __syncthreads();
    int rg = t >> 5, cg = t & 31;
    float4 w0 = *(const float4*)&w0s[cg * 4];
    float4 acc[8];
#pragma unroll
    for (int r = 0; r < 8; ++r) {
        float xv = xs[rg * 8 + r];
        acc[r] = make_float4(xv * w0.x, xv * w0.y, xv * w0.z, xv * w0.w);
    }
    for (int kk = 0; kk < 128; kk += 64) {
        __syncthreads();
        for (int i = t; i < 64 * 128; i += 256) {
            int r = i >> 7, c = i & 127;
            Wt[r][c] = Wenc[128 + (kk + r) * 128 + c];  // rows 1..128
        }
        for (int i = t; i < 64 * 64; i += 256) {
            int r = i >> 6, c = i & 63;
            int n = n0 + r;
            At[r][c] = (n < N) ? preh[(size_t)n * 128 + kk + c] : 0.f;
        }
        __syncthreads();
        mm_tile(Wt, At, acc, rg, cg);
    }
    int colb = cg * 4;
#pragma unroll
    for (int r = 0; r < 8; ++r) {
        int n = n0 + rg * 8 + r;
        if (n < N) {
            float4 v;
            v.x = fmaxf(acc[r].x + bs[colb + 0], 0.f);
            v.y = fmaxf(acc[r].y + bs[colb + 1], 0.f);
            v.z = fmaxf(acc[r].z + bs[colb + 2], 0.f);
            v.w = fmaxf(acc[r].w + bs[colb + 3], 0.f);
            *(float4*)&z[(size_t)n * 128 + colb] = v;
        }
    }
}

// P = z @ W_M[0:128,:]  (blockIdx.y==0),  Q = z @ W_M[128:256,:] (blockIdx.y==1)
__global__ __launch_bounds__(256) void k_pq(
    const float* __restrict__ z, const float* __restrict__ WM,
    float* __restrict__ P, float* __restrict__ Q, int N)
{
    __shared__ float Wt[64][128];
    __shared__ float At[64][65];
    int t = threadIdx.x;
    int n0 = blockIdx.x * 64;
    const float* W = (blockIdx.y == 0) ? WM : WM + 128 * 128;
    float* C = (blockIdx.y == 0) ? P : Q;
    int rg = t >> 5, cg = t & 31;
    float4 acc[8];
#pragma unroll
    for (int r = 0; r < 8; ++r) acc[r] = make_float4(0.f, 0.f, 0.f, 0.f);
    for (int kk = 0; kk < 128; kk += 64) {
        __syncthreads();
        for (int i = t; i < 64 * 128; i += 256) {
            int r = i >> 7, c = i & 127;
            Wt[r][c] = W[(kk + r) * 128 + c];
        }
        for (int i = t; i < 64 * 64; i += 256) {
            int r = i >> 6, c = i & 63;
            int n = n0 + r;
            At[r][c] = (n < N) ? z[(size_t)n * 128 + kk + c] : 0.f;
        }
        __syncthreads();
        mm_tile(Wt, At, acc, rg, cg);
    }
    int colb = cg * 4;
#pragma unroll
    for (int r = 0; r < 8; ++r) {
        int n = n0 + rg * 8 + r;
        if (n < N) *(float4*)&C[(size_t)n * 128 + colb] = acc[r];
    }
}

// Bucket scatter: bucket[dst][slot] = (src, attr). 640k atomics on 50k ctrs.
__global__ __launch_bounds__(256) void k_scatter(
    const int* __restrict__ ei, const float* __restrict__ attr,
    int* __restrict__ cnt, int2* __restrict__ bucket, int E)
{
    int e = blockIdx.x * blockDim.x + threadIdx.x;
    if (e >= E) return;
    int src = ei[e];
    int dst = ei[E + e];
    float a = attr[e];
    int slot = atomicAdd(&cnt[dst], 1);
    if (slot < BCAP)
        bucket[(size_t)dst * BCAP + slot] = make_int2(src, __float_as_int(a));
}

// agg[i] = max(0, P[i] + bM + max_{e in bucket[i]}(Q[src_e] + a_e*w3))
// 32 lanes per node, float4 per lane. agg aliases P (disjoint per-thread RMW).
__global__ __launch_bounds__(256) void k_agg(
    const float* __restrict__ P, const float* __restrict__ Q,
    const int2* __restrict__ bucket, const int* __restrict__ cnt,
    const float* __restrict__ w3, const float* __restrict__ bM,
    float* __restrict__ agg, int N)
{
    int gid = blockIdx.x * blockDim.x + threadIdx.x;
    int i = gid >> 5;
    if (i >= N) return;
    int lane = gid & 31;
    int deg = min(cnt[i], BCAP);
    const int2* b = bucket + (size_t)i * BCAP;
    float4 w = ((const float4*)w3)[lane];
    const float NI = __uint_as_float(0xff800000u);  // -inf
    float4 acc = make_float4(NI, NI, NI, NI);
    int j = 0;
    for (; j + 1 < deg; j += 2) {
        int2 e0 = b[j], e1 = b[j + 1];
        float a0 = __int_as_float(e0.y), a1 = __int_as_float(e1.y);
        float4 q0 = ((const float4*)(Q + (size_t)e0.x * 128))[lane];
        float4 q1 = ((const float4*)(Q + (size_t)e1.x * 128))[lane];
        acc.x = fmaxf(acc.x, fmaf(a0, w.x, q0.x));
        acc.y = fmaxf(acc.y, fmaf(a0, w.y, q0.y));
        acc.z = fmaxf(acc.z, fmaf(a0, w.z, q0.z));
        acc.w = fmaxf(acc.w, fmaf(a0, w.w, q0.w));
        acc.x = fmaxf(acc.x, fmaf(a1, w.x, q1.x));
        acc.y = fmaxf(acc.y, fmaf(a1, w.y, q1.y));
        acc.z = fmaxf(acc.z, fmaf(a1, w.z, q1.z));
        acc.w = fmaxf(acc.w, fmaf(a1, w.w, q1.w));
    }
    if (j < deg) {
        int2 e0 = b[j];
        float a0 = __int_as_float(e0.y);
        float4 q0 = ((const float4*)(Q + (size_t)e0.x * 128))[lane];
        acc.x = fmaxf(acc.x, fmaf(a0, w.x, q0.x));
        acc.y = fmaxf(acc.y, fmaf(a0, w.y, q0.y));
        acc.z = fmaxf(acc.z, fmaf(a0, w.z, q0.z));
        acc.w = fmaxf(acc.w, fmaf(a0, w.w, q0.w));
    }
    float4 p = ((const float4*)(P + (size_t)i * 128))[lane];
    float4 bm = ((const float4*)bM)[lane];
    float4 o;
    o.x = fmaxf(p.x + bm.x + acc.x, 0.f);  // deg==0: -inf -> 0  (matches ref)
    o.y = fmaxf(p.y + bm.y + acc.y, 0.f);
    o.z = fmaxf(p.z + bm.z + acc.z, 0.f);
    o.w = fmaxf(p.w + bm.w + acc.w, 0.f);
    ((float4*)(agg + (size_t)i * 128))[lane] = o;
}

// h = relu(z @ WU[0:128] + agg @ WU[128:256] + bU)
__global__ __launch_bounds__(256) void k_h(
    const float* __restrict__ z, const float* __restrict__ agg,
    const float* __restrict__ WU, const float* __restrict__ bU,
    float* __restrict__ h, int N)
{
    __shared__ float Wt[64][128];
    __shared__ float At[64][65];
    __shared__ float bs[128];
    int t = threadIdx.x;
    int n0 = blockIdx.x * 64;
    if (t < 128) bs[t] = bU[t];
    int rg = t >> 5, cg = t & 31;
    float4 acc[8];
#pragma unroll
    for (int r = 0; r < 8; ++r) acc[r] = make_float4(0.f, 0.f, 0.f, 0.f);
    for (int cc = 0; cc < 4; ++cc) {
        int kk = cc * 64;
        const float* A = (cc < 2) ? z : agg;
        int ko = (cc < 2) ? kk : kk - 128;
        __syncthreads();
        for (int i = t; i < 64 * 128; i += 256) {
            int r = i >> 7, c = i & 127;
            Wt[r][c] = WU[(kk + r) * 128 + c];
        }
        for (int i = t; i < 64 * 64; i += 256) {
            int r = i >> 6, c = i & 63;
            int n = n0 + r;
            At[r][c] = (n < N) ? A[(size_t)n * 128 + ko + c] : 0.f;
        }
        __syncthreads();
        mm_tile(Wt, At, acc, rg, cg);
    }
    int colb = cg * 4;
#pragma unroll
    for (int r = 0; r < 8; ++r) {
        int n = n0 + rg * 8 + r;
        if (n < N) {
            float4 v;
            v.x = fmaxf(acc[r].x + bs[colb + 0], 0.f);
            v.y = fmaxf(acc[r].y + bs[colb + 1], 0.f);
            v.z = fmaxf(acc[r].z + bs[colb + 2], 0.f);
            v.w = fmaxf(acc[r].w + bs[colb + 3], 0.f);
            *(float4*)&h[(size_t)n * 128 + colb] = v;
        }
    }
}

// y[n] = [z[n], h[n]] . W_dec + b_dec — one wave per node (grid-stride)
__global__ __launch_bounds__(256) void k_y(
    const float* __restrict__ z, const float* __restrict__ h,
    const float* __restrict__ Wd, const float* __restrict__ bd,
    float* __restrict__ y, int N)
{
    int tid = blockIdx.x * blockDim.x + threadIdx.x;
    int wid = tid >> 6, lane = tid & 63;
    int nw = (gridDim.x * blockDim.x) >> 6;
    float wz0 = Wd[lane], wz1 = Wd[64 + lane];
    float wh0 = Wd[128 + lane], wh1 = Wd[192 + lane];
    float bb = bd[0];
    for (int n = wid; n < N; n += nw) {
        const float* zr = z + (size_t)n * 128;
        const float* hr = h + (size_t)n * 128;
        float p = zr[lane] * wz0 + zr[64 + lane] * wz1 +
                  hr[lane] * wh0 + hr[64 + lane] * wh1;
#pragma unroll
        for (int o = 32; o > 0; o >>= 1) p += __shfl_down(p, o, 64);
        if (lane == 0) y[n] = p + bb;
    }
}

// column sums of h -> hsum[128]
__global__ __launch_bounds__(256) void k_hsum(
    const float* __restrict__ h, float* __restrict__ hsum, int N)
{
    __shared__ float sd[256];
    int t = threadIdx.x;
    int rows = (N + gridDim.x - 1) / gridDim.x;
    int nstart = blockIdx.x * rows;
    int nend = min(nstart + rows, N);
    int col = t & 127, half = t >> 7;
    float acc = 0.f;
    for (int n = nstart + half; n < nend; n += 2)
        acc += h[(size_t)n * 128 + col];
    sd[t] = acc;
    __syncthreads();
    if (t < 128) atomicAdd(&hsum[t], sd[t] + sd[t + 128]);
}

// tau = (hsum/N) . (W_term[0:128] + W_term[128:256]) + b_term
__global__ __launch_bounds__(128) void k_tau(
    const float* __restrict__ hsum, const float* __restrict__ Wt,
    const float* __restrict__ bt, float* __restrict__ tau, int N)
{
    __shared__ float sd[128];
    int t = threadIdx.x;
    float v = hsum[t] * (1.f / (float)N) * (Wt[t] + Wt[128 + t]);
    sd[t] = v;
    __syncthreads();
    for (int s = 64; s > 0; s >>= 1) {
        if (t < s) sd[t] += sd[t + s];
        __syncthreads();
    }
    if (t == 0) tau[0] = sd[0] + bt[0];
}

extern "C" void kernel_launch(void* const* d_in, const int* in_sizes, int n_in,
                              void* d_out, int out_size, void* d_ws, size_t ws_size,
                              hipStream_t stream)
{
    const float* x     = (const float*)d_in[0];
    const float* preh  = (const float*)d_in[1];
    const int*   ei    = (const int*)d_in[2];
    const float* attr  = (const float*)d_in[3];
    const float* Wenc  = (const float*)d_in[4];
    const float* benc  = (const float*)d_in[5];
    const float* WM    = (const float*)d_in[6];
    const float* bM    = (const float*)d_in[7];
    const float* WU    = (const float*)d_in[8];
    const float* bU    = (const float*)d_in[9];
    const float* Wd    = (const float*)d_in[10];
    const float* bd    = (const float*)d_in[11];
    const float* Wterm = (const float*)d_in[12];
    const float* bterm = (const float*)d_in[13];
    int N = in_sizes[0];
    int E = in_sizes[3];

    float* z      = (float*)d_ws;
    float* P      = z + (size_t)N * 128;        // becomes agg in-place
    float* Qb     = P + (size_t)N * 128;
    int2*  bucket = (int2*)(Qb + (size_t)N * 128);  // N*BCAP int2
    int*   cnt    = (int*)(bucket + (size_t)N * BCAP);
    float* hsum   = (float*)(cnt + N);

    float* hout = (float*)d_out;
    float* yout = hout + (size_t)N * 128;
    float* tau  = yout + N;

    int nb = (N + 63) / 64;
    // zero cnt and hsum in one shot (contiguous)
    hipMemsetAsync(cnt, 0, ((size_t)N + 128) * sizeof(int), stream);

    k_enc<<<nb, 256, 0, stream>>>(x, preh, Wenc, benc, z, N);
    k_pq<<<dim3(nb, 2), 256, 0, stream>>>(z, WM, P, Qb, N);
    k_scatter<<<(E + 255) / 256, 256, 0, stream>>>(ei, attr, cnt, bucket, E);
    k_agg<<<(N * 32 + 255) / 256, 256, 0, stream>>>(P, Qb, bucket, cnt,
                                                    WM + 256 * 128, bM, P, N);
    k_h<<<nb, 256, 0, stream>>>(z, P, WU, bU, hout, N);
    k_y<<<256, 256, 0, stream>>>(z, hout, Wd, bd, yout, N);
    k_hsum<<<128, 256, 0, stream>>>(hout, hsum, N);
    k_tau<<<1, 128, 0, stream>>>(hsum, Wterm, bterm, tau, N);
}

// Round 3
// 346.332 us; speedup vs baseline: 3.5613x; 1.3595x over previous
//
#include <hip/hip_runtime.h>

#define DEVINL __device__ __forceinline__
#define BCAP 64  // bucket capacity per node; deg~Poisson(12.8), P(>64)~3e-23

typedef __attribute__((ext_vector_type(8))) short short8;
typedef __attribute__((ext_vector_type(4))) float f32x4;
typedef __attribute__((ext_vector_type(4))) unsigned short ushort4v;
typedef __attribute__((ext_vector_type(8))) unsigned short ushort8v;

DEVINL unsigned short f2bf(float f) {  // RNE float->bf16
    unsigned u = __float_as_uint(f);
    u += 0x7fffu + ((u >> 16) & 1u);
    return (unsigned short)(u >> 16);
}
DEVINL float bf2f(unsigned short s) { return __uint_as_float(((unsigned)s) << 16); }

// Transpose + bf16-convert all weights once. WT[col][k] layouts.
__global__ __launch_bounds__(256) void k_prepw(
    const float* __restrict__ Wenc, const float* __restrict__ WM,
    const float* __restrict__ WU,
    unsigned short* __restrict__ WencT, unsigned short* __restrict__ WM1T,
    unsigned short* __restrict__ WM2T, unsigned short* __restrict__ WUT)
{
    int tid = blockIdx.x * blockDim.x + threadIdx.x;
    int nt = gridDim.x * blockDim.x;
    for (int i = tid; i < 128 * 128; i += nt) {
        int c = i >> 7, k = i & 127;
        WencT[c * 128 + k] = f2bf(Wenc[(1 + k) * 128 + c]);  // rows 1..128
        WM1T[c * 128 + k]  = f2bf(WM[k * 128 + c]);
        WM2T[c * 128 + k]  = f2bf(WM[(128 + k) * 128 + c]);
    }
    for (int i = tid; i < 128 * 256; i += nt) {
        int c = i >> 8, k = i & 255;
        WUT[c * 256 + k] = f2bf(WU[k * 128 + c]);
    }
}

// ---- MFMA GEMM, no LDS. Block = 4 waves, 64 nodes x 128 cols.
// Wave: 16 nodes x 128 cols = 8 mfma tiles. Operands swapped (WT is the
// M-operand) so each lane's C regs are 4 consecutive output cols at one node.
// A'(first op)[m=lane&15][k=quad*8+j] = WT[t*16+m][k]   (16B contiguous)
// B'(second)[k][n=lane&15]            = Arow[node=n][k] (16B contiguous)
// D: node = lane&15, cols = t*16 + quad*4 + r.

// z = relu([x, pre_h] @ W_enc + b_enc) -> zc[:,0:128] bf16 (row stride 256)
__global__ __launch_bounds__(256) void k_enc(
    const float* __restrict__ x, const float* __restrict__ preh,
    const unsigned short* __restrict__ WencT, const float* __restrict__ Wenc,
    const float* __restrict__ benc, unsigned short* __restrict__ zc, int N)
{
    int t = threadIdx.x;
    int wave = t >> 6, lane = t & 63;
    int m = lane & 15, quad = lane >> 4;
    int node = blockIdx.x * 64 + wave * 16 + m;
    int nodec = min(node, N - 1);
    f32x4 acc[8];
#pragma unroll
    for (int i = 0; i < 8; ++i) acc[i] = (f32x4)0.f;
    const float* arow = preh + (size_t)nodec * 128;
#pragma unroll
    for (int kc = 0; kc < 4; ++kc) {
        int k0 = kc * 32 + quad * 8;
        float4 f0 = *(const float4*)(arow + k0);
        float4 f1 = *(const float4*)(arow + k0 + 4);
        short8 bfrag;
        bfrag[0] = (short)f2bf(f0.x); bfrag[1] = (short)f2bf(f0.y);
        bfrag[2] = (short)f2bf(f0.z); bfrag[3] = (short)f2bf(f0.w);
        bfrag[4] = (short)f2bf(f1.x); bfrag[5] = (short)f2bf(f1.y);
        bfrag[6] = (short)f2bf(f1.z); bfrag[7] = (short)f2bf(f1.w);
#pragma unroll
        for (int t8 = 0; t8 < 8; ++t8) {
            short8 afrag = *(const short8*)(WencT + (size_t)(t8 * 16 + m) * 128 + k0);
            acc[t8] = __builtin_amdgcn_mfma_f32_16x16x32_bf16(afrag, bfrag, acc[t8], 0, 0, 0);
        }
    }
    if (node >= N) return;
    float xv = x[node];
    unsigned short* orow = zc + (size_t)node * 256;
#pragma unroll
    for (int t8 = 0; t8 < 8; ++t8) {
        int col = t8 * 16 + quad * 4;
        float4 w0v = *(const float4*)(Wenc + col);  // row 0 of W_enc = x weights
        float4 bv  = *(const float4*)(benc + col);
        ushort4v o;
        o[0] = f2bf(fmaxf(acc[t8][0] + xv * w0v.x + bv.x, 0.f));
        o[1] = f2bf(fmaxf(acc[t8][1] + xv * w0v.y + bv.y, 0.f));
        o[2] = f2bf(fmaxf(acc[t8][2] + xv * w0v.z + bv.z, 0.f));
        o[3] = f2bf(fmaxf(acc[t8][3] + xv * w0v.w + bv.w, 0.f));
        *(ushort4v*)(orow + col) = o;
    }
}

// P = z@WM1 (blockIdx.y=0) / Q = z@WM2 (blockIdx.y=1), bf16 in/out
__global__ __launch_bounds__(256) void k_pq(
    const unsigned short* __restrict__ zc,
    const unsigned short* __restrict__ WM1T, const unsigned short* __restrict__ WM2T,
    unsigned short* __restrict__ Pb, unsigned short* __restrict__ Qb, int N)
{
    const unsigned short* WT = blockIdx.y ? WM2T : WM1T;
    unsigned short* out = blockIdx.y ? Qb : Pb;
    int t = threadIdx.x;
    int wave = t >> 6, lane = t & 63;
    int m = lane & 15, quad = lane >> 4;
    int node = blockIdx.x * 64 + wave * 16 + m;
    int nodec = min(node, N - 1);
    f32x4 acc[8];
#pragma unroll
    for (int i = 0; i < 8; ++i) acc[i] = (f32x4)0.f;
    const unsigned short* arow = zc + (size_t)nodec * 256;
#pragma unroll
    for (int kc = 0; kc < 4; ++kc) {
        int k0 = kc * 32 + quad * 8;
        short8 bfrag = *(const short8*)(arow + k0);
#pragma unroll
        for (int t8 = 0; t8 < 8; ++t8) {
            short8 afrag = *(const short8*)(WT + (size_t)(t8 * 16 + m) * 128 + k0);
            acc[t8] = __builtin_amdgcn_mfma_f32_16x16x32_bf16(afrag, bfrag, acc[t8], 0, 0, 0);
        }
    }
    if (node >= N) return;
    unsigned short* orow = out + (size_t)node * 128;
#pragma unroll
    for (int t8 = 0; t8 < 8; ++t8) {
        int col = t8 * 16 + quad * 4;
        ushort4v o;
        o[0] = f2bf(acc[t8][0]); o[1] = f2bf(acc[t8][1]);
        o[2] = f2bf(acc[t8][2]); o[3] = f2bf(acc[t8][3]);
        *(ushort4v*)(orow + col) = o;
    }
}

// h = relu([z|agg] @ W_U + b_U) -> fp32 d_out; A = zc [N][256] bf16, K=256
__global__ __launch_bounds__(256) void k_h(
    const unsigned short* __restrict__ zc, const unsigned short* __restrict__ WUT,
    const float* __restrict__ bU, float* __restrict__ h, int N)
{
    int t = threadIdx.x;
    int wave = t >> 6, lane = t & 63;
    int m = lane & 15, quad = lane >> 4;
    int node = blockIdx.x * 64 + wave * 16 + m;
    int nodec = min(node, N - 1);
    f32x4 acc[8];
#pragma unroll
    for (int i = 0; i < 8; ++i) acc[i] = (f32x4)0.f;
    const unsigned short* arow = zc + (size_t)nodec * 256;
#pragma unroll
    for (int kc = 0; kc < 8; ++kc) {
        int k0 = kc * 32 + quad * 8;
        short8 bfrag = *(const short8*)(arow + k0);
#pragma unroll
        for (int t8 = 0; t8 < 8; ++t8) {
            short8 afrag = *(const short8*)(WUT + (size_t)(t8 * 16 + m) * 256 + k0);
            acc[t8] = __builtin_amdgcn_mfma_f32_16x16x32_bf16(afrag, bfrag, acc[t8], 0, 0, 0);
        }
    }
    if (node >= N) return;
    float* orow = h + (size_t)node * 128;
#pragma unroll
    for (int t8 = 0; t8 < 8; ++t8) {
        int col = t8 * 16 + quad * 4;
        float4 bv = *(const float4*)(bU + col);
        float4 o;
        o.x = fmaxf(acc[t8][0] + bv.x, 0.f);
        o.y = fmaxf(acc[t8][1] + bv.y, 0.f);
        o.z = fmaxf(acc[t8][2] + bv.z, 0.f);
        o.w = fmaxf(acc[t8][3] + bv.w, 0.f);
        *(float4*)(orow + col) = o;
    }
}

// Bucket scatter: bucket[dst][slot] = (src, attr). 640k atomics on 50k ctrs.
__global__ __launch_bounds__(256) void k_scatter(
    const int* __restrict__ ei, const float* __restrict__ attr,
    int* __restrict__ cnt, int2* __restrict__ bucket, int E)
{
    int e = blockIdx.x * blockDim.x + threadIdx.x;
    if (e >= E) return;
    int src = ei[e];
    int dst = ei[E + e];
    float a = attr[e];
    int slot = atomicAdd(&cnt[dst], 1);
    if (slot < BCAP)
        bucket[(size_t)dst * BCAP + slot] = make_int2(src, __float_as_int(a));
}

// agg[i] = max(0, P[i] + bM + max_e(Q[src_e] + a_e*w3)) -> zc[:,128:256] bf16
// 16 lanes per node, 8 cols/lane (16B bf16 gathers of Q rows).
__global__ __launch_bounds__(256) void k_agg(
    const unsigned short* __restrict__ Pb, const unsigned short* __restrict__ Qb,
    const int2* __restrict__ bucket, const int* __restrict__ cnt,
    const float* __restrict__ w3, const float* __restrict__ bM,
    unsigned short* __restrict__ zc, int N)
{
    int gid = blockIdx.x * blockDim.x + threadIdx.x;
    int i = gid >> 4;
    if (i >= N) return;
    int lane = gid & 15;
    int c0 = lane * 8;
    int deg = min(cnt[i], BCAP);
    const int2* b = bucket + (size_t)i * BCAP;
    float w[8], acc[8];
    {
        float4 wa = *(const float4*)(w3 + c0), wb = *(const float4*)(w3 + c0 + 4);
        w[0] = wa.x; w[1] = wa.y; w[2] = wa.z; w[3] = wa.w;
        w[4] = wb.x; w[5] = wb.y; w[6] = wb.z; w[7] = wb.w;
    }
    const float NI = __uint_as_float(0xff800000u);
#pragma unroll
    for (int u = 0; u < 8; ++u) acc[u] = NI;
    int j = 0;
    for (; j + 1 < deg; j += 2) {
        int2 e0 = b[j], e1 = b[j + 1];
        float a0 = __int_as_float(e0.y), a1 = __int_as_float(e1.y);
        short8 q0 = *(const short8*)(Qb + (size_t)e0.x * 128 + c0);
        short8 q1 = *(const short8*)(Qb + (size_t)e1.x * 128 + c0);
#pragma unroll
        for (int u = 0; u < 8; ++u)
            acc[u] = fmaxf(acc[u], fmaf(a0, w[u], bf2f((unsigned short)q0[u])));
#pragma unroll
        for (int u = 0; u < 8; ++u)
            acc[u] = fmaxf(acc[u], fmaf(a1, w[u], bf2f((unsigned short)q1[u])));
    }
    if (j < deg) {
        int2 e0 = b[j];
        float a0 = __int_as_float(e0.y);
        short8 q0 = *(const short8*)(Qb + (size_t)e0.x * 128 + c0);
#pragma unroll
        for (int u = 0; u < 8; ++u)
            acc[u] = fmaxf(acc[u], fmaf(a0, w[u], bf2f((unsigned short)q0[u])));
    }
    short8 p = *(const short8*)(Pb + (size_t)i * 128 + c0);
    float4 ba = *(const float4*)(bM + c0), bb = *(const float4*)(bM + c0 + 4);
    float bm[8] = {ba.x, ba.y, ba.z, ba.w, bb.x, bb.y, bb.z, bb.w};
    ushort8v o;
#pragma unroll
    for (int u = 0; u < 8; ++u)  // deg==0: -inf -> relu 0 (matches ref)
        o[u] = f2bf(fmaxf(bf2f((unsigned short)p[u]) + bm[u] + acc[u], 0.f));
    *(ushort8v*)(zc + (size_t)i * 256 + 128 + c0) = o;
}

// y[n] = [z[n], h[n]] . W_dec + b_dec — one wave per node (grid-stride)
__global__ __launch_bounds__(256) void k_y(
    const unsigned short* __restrict__ zc, const float* __restrict__ h,
    const float* __restrict__ Wd, const float* __restrict__ bd,
    float* __restrict__ y, int N)
{
    int tid = blockIdx.x * blockDim.x + threadIdx.x;
    int wid = tid >> 6, lane = tid & 63;
    int nw = (gridDim.x * blockDim.x) >> 6;
    float wz0 = Wd[lane], wz1 = Wd[64 + lane];
    float wh0 = Wd[128 + lane], wh1 = Wd[192 + lane];
    float bb = bd[0];
    for (int n = wid; n < N; n += nw) {
        const unsigned short* zr = zc + (size_t)n * 256;
        const float* hr = h + (size_t)n * 128;
        float p = bf2f(zr[lane]) * wz0 + bf2f(zr[64 + lane]) * wz1 +
                  hr[lane] * wh0 + hr[64 + lane] * wh1;
#pragma unroll
        for (int o = 32; o > 0; o >>= 1) p += __shfl_down(p, o, 64);
        if (lane == 0) y[n] = p + bb;
    }
}

// column sums of h -> hsum[128]
__global__ __launch_bounds__(256) void k_hsum(
    const float* __restrict__ h, float* __restrict__ hsum, int N)
{
    __shared__ float sd[256];
    int t = threadIdx.x;
    int rows = (N + gridDim.x - 1) / gridDim.x;
    int nstart = blockIdx.x * rows;
    int nend = min(nstart + rows, N);
    int col = t & 127, half = t >> 7;
    float acc = 0.f;
    for (int n = nstart + half; n < nend; n += 2)
        acc += h[(size_t)n * 128 + col];
    sd[t] = acc;
    __syncthreads();
    if (t < 128) atomicAdd(&hsum[t], sd[t] + sd[t + 128]);
}

// tau = (hsum/N) . (W_term[0:128] + W_term[128:256]) + b_term
__global__ __launch_bounds__(128) void k_tau(
    const float* __restrict__ hsum, const float* __restrict__ Wt,
    const float* __restrict__ bt, float* __restrict__ tau, int N)
{
    __shared__ float sd[128];
    int t = threadIdx.x;
    float v = hsum[t] * (1.f / (float)N) * (Wt[t] + Wt[128 + t]);
    sd[t] = v;
    __syncthreads();
    for (int s = 64; s > 0; s >>= 1) {
        if (t < s) sd[t] += sd[t + s];
        __syncthreads();
    }
    if (t == 0) tau[0] = sd[0] + bt[0];
}

extern "C" void kernel_launch(void* const* d_in, const int* in_sizes, int n_in,
                              void* d_out, int out_size, void* d_ws, size_t ws_size,
                              hipStream_t stream)
{
    const float* x     = (const float*)d_in[0];
    const float* preh  = (const float*)d_in[1];
    const int*   ei    = (const int*)d_in[2];
    const float* attr  = (const float*)d_in[3];
    const float* Wenc  = (const float*)d_in[4];
    const float* benc  = (const float*)d_in[5];
    const float* WM    = (const float*)d_in[6];
    const float* bM    = (const float*)d_in[7];
    const float* WU    = (const float*)d_in[8];
    const float* bU    = (const float*)d_in[9];
    const float* Wd    = (const float*)d_in[10];
    const float* bd    = (const float*)d_in[11];
    const float* Wterm = (const float*)d_in[12];
    const float* bterm = (const float*)d_in[13];
    int N = in_sizes[0];
    int E = in_sizes[3];

    char* wp = (char*)d_ws;
    unsigned short* zc    = (unsigned short*)wp; wp += (size_t)N * 256 * 2;
    unsigned short* Pb    = (unsigned short*)wp; wp += (size_t)N * 128 * 2;
    unsigned short* Qb    = (unsigned short*)wp; wp += (size_t)N * 128 * 2;
    int2*           bucket= (int2*)wp;           wp += (size_t)N * BCAP * 8;
    int*            cnt   = (int*)wp;            wp += (size_t)N * 4;
    float*          hsum  = (float*)wp;          wp += 128 * 4;
    unsigned short* WencT = (unsigned short*)wp; wp += 128 * 128 * 2;
    unsigned short* WM1T  = (unsigned short*)wp; wp += 128 * 128 * 2;
    unsigned short* WM2T  = (unsigned short*)wp; wp += 128 * 128 * 2;
    unsigned short* WUT   = (unsigned short*)wp; wp += 128 * 256 * 2;

    float* hout = (float*)d_out;
    float* yout = hout + (size_t)N * 128;
    float* tau  = yout + N;

    int nb = (N + 63) / 64;
    hipMemsetAsync(cnt, 0, ((size_t)N + 128) * sizeof(int), stream);

    k_prepw<<<64, 256, 0, stream>>>(Wenc, WM, WU, WencT, WM1T, WM2T, WUT);
    k_enc<<<nb, 256, 0, stream>>>(x, preh, WencT, Wenc, benc, zc, N);
    k_pq<<<dim3(nb, 2), 256, 0, stream>>>(zc, WM1T, WM2T, Pb, Qb, N);
    k_scatter<<<(E + 255) / 256, 256, 0, stream>>>(ei, attr, cnt, bucket, E);
    k_agg<<<(N * 16 + 255) / 256, 256, 0, stream>>>(Pb, Qb, bucket, cnt,
                                                    WM + 256 * 128, bM, zc, N);
    k_h<<<nb, 256, 0, stream>>>(zc, WUT, bU, hout, N);
    k_y<<<256, 256, 0, stream>>>(zc, hout, Wd, bd, yout, N);
    k_hsum<<<128, 256, 0, stream>>>(hout, hsum, N);
    k_tau<<<1, 128, 0, stream>>>(hsum, Wterm, bterm, tau, N);
}

// Round 4
// 290.184 us; speedup vs baseline: 4.2504x; 1.1935x over previous
//
#include <hip/hip_runtime.h>

#define DEVINL __device__ __forceinline__
#define BCAP 64  // bucket capacity per node; deg~Poisson(12.8), P(>64)~3e-23

typedef __attribute__((ext_vector_type(8))) short short8;
typedef __attribute__((ext_vector_type(4))) float f32x4;
typedef __attribute__((ext_vector_type(4))) unsigned short ushort4v;
typedef __attribute__((ext_vector_type(8))) unsigned short ushort8v;

DEVINL unsigned short f2bf(float f) {  // RNE float->bf16
    unsigned u = __float_as_uint(f);
    u += 0x7fffu + ((u >> 16) & 1u);
    return (unsigned short)(u >> 16);
}
DEVINL float bf2f(unsigned short s) { return __uint_as_float(((unsigned)s) << 16); }

// Transpose + bf16-convert all weights once. WT[col][k] layouts.
__global__ __launch_bounds__(256) void k_prepw(
    const float* __restrict__ Wenc, const float* __restrict__ WM,
    const float* __restrict__ WU,
    unsigned short* __restrict__ WencT, unsigned short* __restrict__ WM1T,
    unsigned short* __restrict__ WM2T, unsigned short* __restrict__ WUT)
{
    int tid = blockIdx.x * blockDim.x + threadIdx.x;
    int nt = gridDim.x * blockDim.x;
    for (int i = tid; i < 128 * 128; i += nt) {
        int c = i >> 7, k = i & 127;
        WencT[c * 128 + k] = f2bf(Wenc[(1 + k) * 128 + c]);  // rows 1..128
        WM1T[c * 128 + k]  = f2bf(WM[k * 128 + c]);
        WM2T[c * 128 + k]  = f2bf(WM[(128 + k) * 128 + c]);
    }
    for (int i = tid; i < 128 * 256; i += nt) {
        int c = i >> 8, k = i & 255;
        WUT[c * 256 + k] = f2bf(WU[k * 128 + c]);
    }
}

// ---- MFMA GEMM, no LDS. Block = 4 waves, 64 nodes x 128 cols.
// Wave: 16 nodes x 128 cols = 8 mfma tiles. Operands swapped (WT is the
// M-operand) so each lane's C regs are 4 consecutive output cols at one node.
// D: node = lane&15, cols = t8*16 + (lane>>4)*4 + r.

// z = relu([x, pre_h] @ W_enc + b_enc) -> zc[:,0:128] bf16 (row stride 256)
__global__ __launch_bounds__(256) void k_enc(
    const float* __restrict__ x, const float* __restrict__ preh,
    const unsigned short* __restrict__ WencT, const float* __restrict__ Wenc,
    const float* __restrict__ benc, unsigned short* __restrict__ zc, int N)
{
    int t = threadIdx.x;
    int wave = t >> 6, lane = t & 63;
    int m = lane & 15, quad = lane >> 4;
    int node = blockIdx.x * 64 + wave * 16 + m;
    int nodec = min(node, N - 1);
    f32x4 acc[8];
#pragma unroll
    for (int i = 0; i < 8; ++i) acc[i] = (f32x4)0.f;
    const float* arow = preh + (size_t)nodec * 128;
#pragma unroll
    for (int kc = 0; kc < 4; ++kc) {
        int k0 = kc * 32 + quad * 8;
        float4 f0 = *(const float4*)(arow + k0);
        float4 f1 = *(const float4*)(arow + k0 + 4);
        short8 bfrag;
        bfrag[0] = (short)f2bf(f0.x); bfrag[1] = (short)f2bf(f0.y);
        bfrag[2] = (short)f2bf(f0.z); bfrag[3] = (short)f2bf(f0.w);
        bfrag[4] = (short)f2bf(f1.x); bfrag[5] = (short)f2bf(f1.y);
        bfrag[6] = (short)f2bf(f1.z); bfrag[7] = (short)f2bf(f1.w);
#pragma unroll
        for (int t8 = 0; t8 < 8; ++t8) {
            short8 afrag = *(const short8*)(WencT + (size_t)(t8 * 16 + m) * 128 + k0);
            acc[t8] = __builtin_amdgcn_mfma_f32_16x16x32_bf16(afrag, bfrag, acc[t8], 0, 0, 0);
        }
    }
    if (node >= N) return;
    float xv = x[node];
    unsigned short* orow = zc + (size_t)node * 256;
#pragma unroll
    for (int t8 = 0; t8 < 8; ++t8) {
        int col = t8 * 16 + quad * 4;
        float4 w0v = *(const float4*)(Wenc + col);  // row 0 of W_enc = x weights
        float4 bv  = *(const float4*)(benc + col);
        ushort4v o;
        o[0] = f2bf(fmaxf(acc[t8][0] + xv * w0v.x + bv.x, 0.f));
        o[1] = f2bf(fmaxf(acc[t8][1] + xv * w0v.y + bv.y, 0.f));
        o[2] = f2bf(fmaxf(acc[t8][2] + xv * w0v.z + bv.z, 0.f));
        o[3] = f2bf(fmaxf(acc[t8][3] + xv * w0v.w + bv.w, 0.f));
        *(ushort4v*)(orow + col) = o;
    }
}

// P = z@WM1 and Q = z@WM2 in one pass (bfrag shared), bf16 in/out
__global__ __launch_bounds__(256) void k_pq(
    const unsigned short* __restrict__ zc,
    const unsigned short* __restrict__ WM1T, const unsigned short* __restrict__ WM2T,
    unsigned short* __restrict__ Pb, unsigned short* __restrict__ Qb, int N)
{
    int t = threadIdx.x;
    int wave = t >> 6, lane = t & 63;
    int m = lane & 15, quad = lane >> 4;
    int node = blockIdx.x * 64 + wave * 16 + m;
    int nodec = min(node, N - 1);
    f32x4 accP[8], accQ[8];
#pragma unroll
    for (int i = 0; i < 8; ++i) { accP[i] = (f32x4)0.f; accQ[i] = (f32x4)0.f; }
    const unsigned short* arow = zc + (size_t)nodec * 256;
#pragma unroll
    for (int kc = 0; kc < 4; ++kc) {
        int k0 = kc * 32 + quad * 8;
        short8 bfrag = *(const short8*)(arow + k0);
#pragma unroll
        for (int t8 = 0; t8 < 8; ++t8) {
            size_t wo = (size_t)(t8 * 16 + m) * 128 + k0;
            short8 a1 = *(const short8*)(WM1T + wo);
            accP[t8] = __builtin_amdgcn_mfma_f32_16x16x32_bf16(a1, bfrag, accP[t8], 0, 0, 0);
            short8 a2 = *(const short8*)(WM2T + wo);
            accQ[t8] = __builtin_amdgcn_mfma_f32_16x16x32_bf16(a2, bfrag, accQ[t8], 0, 0, 0);
        }
    }
    if (node >= N) return;
    unsigned short* prow = Pb + (size_t)node * 128;
    unsigned short* qrow = Qb + (size_t)node * 128;
#pragma unroll
    for (int t8 = 0; t8 < 8; ++t8) {
        int col = t8 * 16 + quad * 4;
        ushort4v op, oq;
        op[0] = f2bf(accP[t8][0]); op[1] = f2bf(accP[t8][1]);
        op[2] = f2bf(accP[t8][2]); op[3] = f2bf(accP[t8][3]);
        oq[0] = f2bf(accQ[t8][0]); oq[1] = f2bf(accQ[t8][1]);
        oq[2] = f2bf(accQ[t8][2]); oq[3] = f2bf(accQ[t8][3]);
        *(ushort4v*)(prow + col) = op;
        *(ushort4v*)(qrow + col) = oq;
    }
}

// h = relu([z|agg] @ W_U + b_U) -> fp32 d_out;  FUSED: y, hsum epilogues.
__global__ __launch_bounds__(256) void k_h(
    const unsigned short* __restrict__ zc, const unsigned short* __restrict__ WUT,
    const float* __restrict__ bU, const float* __restrict__ Wd,
    const float* __restrict__ bd, float* __restrict__ h,
    float* __restrict__ y, float* __restrict__ hsum, int N)
{
    __shared__ float hs[4][128];  // per-wave column partial sums
    int t = threadIdx.x;
    int wave = t >> 6, lane = t & 63;
    int m = lane & 15, quad = lane >> 4;
    int node = blockIdx.x * 64 + wave * 16 + m;
    bool valid = node < N;
    int nodec = min(node, N - 1);
    f32x4 acc[8];
#pragma unroll
    for (int i = 0; i < 8; ++i) acc[i] = (f32x4)0.f;
    float py = 0.f;  // y partial: z-part during K-loop, h-part in epilogue
    const unsigned short* arow = zc + (size_t)nodec * 256;
#pragma unroll
    for (int kc = 0; kc < 8; ++kc) {
        int k0 = kc * 32 + quad * 8;
        short8 bfrag = *(const short8*)(arow + k0);
        if (kc < 4) {  // bfrag holds z[node][k0..k0+7]; y's z·Wd[:128] term
            float4 wa = *(const float4*)(Wd + k0);
            float4 wb = *(const float4*)(Wd + k0 + 4);
            py += bf2f((unsigned short)bfrag[0]) * wa.x
                + bf2f((unsigned short)bfrag[1]) * wa.y
                + bf2f((unsigned short)bfrag[2]) * wa.z
                + bf2f((unsigned short)bfrag[3]) * wa.w
                + bf2f((unsigned short)bfrag[4]) * wb.x
                + bf2f((unsigned short)bfrag[5]) * wb.y
                + bf2f((unsigned short)bfrag[6]) * wb.z
                + bf2f((unsigned short)bfrag[7]) * wb.w;
        }
#pragma unroll
        for (int t8 = 0; t8 < 8; ++t8) {
            short8 afrag = *(const short8*)(WUT + (size_t)(t8 * 16 + m) * 256 + k0);
            acc[t8] = __builtin_amdgcn_mfma_f32_16x16x32_bf16(afrag, bfrag, acc[t8], 0, 0, 0);
        }
    }
    const float* Wdh = Wd + 128;
    float* orow = h + (size_t)node * 128;
#pragma unroll
    for (int t8 = 0; t8 < 8; ++t8) {
        int col = t8 * 16 + quad * 4;
        float4 bv = *(const float4*)(bU + col);
        float4 o;  // zeroed for invalid nodes so hsum stays exact
        o.x = valid ? fmaxf(acc[t8][0] + bv.x, 0.f) : 0.f;
        o.y = valid ? fmaxf(acc[t8][1] + bv.y, 0.f) : 0.f;
        o.z = valid ? fmaxf(acc[t8][2] + bv.z, 0.f) : 0.f;
        o.w = valid ? fmaxf(acc[t8][3] + bv.w, 0.f) : 0.f;
        if (valid) *(float4*)(orow + col) = o;
        float4 wd = *(const float4*)(Wdh + col);
        py += o.x * wd.x + o.y * wd.y + o.z * wd.z + o.w * wd.w;
        // reduce across the 16 m-lanes (same cols, different nodes)
        float4 s = o;
#pragma unroll
        for (int mask = 1; mask <= 8; mask <<= 1) {
            s.x += __shfl_xor(s.x, mask, 64);
            s.y += __shfl_xor(s.y, mask, 64);
            s.z += __shfl_xor(s.z, mask, 64);
            s.w += __shfl_xor(s.w, mask, 64);
        }
        if (m == 0) *(float4*)&hs[wave][col] = s;
    }
    // y: reduce py across the 4 quad-lanes of this node
    py += __shfl_xor(py, 16, 64);
    py += __shfl_xor(py, 32, 64);
    if (quad == 0 && valid) y[node] = py + bd[0];
    __syncthreads();
    if (t < 128) {
        float v = hs[0][t] + hs[1][t] + hs[2][t] + hs[3][t];
        atomicAdd(&hsum[t], v);
    }
}

// Bucket scatter: bucket[dst][slot] = (src, attr). 640k atomics on 50k ctrs.
__global__ __launch_bounds__(256) void k_scatter(
    const int* __restrict__ ei, const float* __restrict__ attr,
    int* __restrict__ cnt, int2* __restrict__ bucket, int E)
{
    int e = blockIdx.x * blockDim.x + threadIdx.x;
    if (e >= E) return;
    int src = ei[e];
    int dst = ei[E + e];
    float a = attr[e];
    int slot = atomicAdd(&cnt[dst], 1);
    if (slot < BCAP)
        bucket[(size_t)dst * BCAP + slot] = make_int2(src, __float_as_int(a));
}

// agg[i] = max(0, P[i] + bM + max_e(Q[src_e] + a_e*w3)) -> zc[:,128:256] bf16
// 16 lanes per node, 8 cols/lane (16B bf16 gathers of Q rows), 4-deep MLP.
__global__ __launch_bounds__(256) void k_agg(
    const unsigned short* __restrict__ Pb, const unsigned short* __restrict__ Qb,
    const int2* __restrict__ bucket, const int* __restrict__ cnt,
    const float* __restrict__ w3, const float* __restrict__ bM,
    unsigned short* __restrict__ zc, int N)
{
    int gid = blockIdx.x * blockDim.x + threadIdx.x;
    int i = gid >> 4;
    if (i >= N) return;
    int lane = gid & 15;
    int c0 = lane * 8;
    int deg = min(cnt[i], BCAP);
    const int2* b = bucket + (size_t)i * BCAP;
    float w[8], acc[8];
    {
        float4 wa = *(const float4*)(w3 + c0), wb = *(const float4*)(w3 + c0 + 4);
        w[0] = wa.x; w[1] = wa.y; w[2] = wa.z; w[3] = wa.w;
        w[4] = wb.x; w[5] = wb.y; w[6] = wb.z; w[7] = wb.w;
    }
    const float NI = __uint_as_float(0xff800000u);
#pragma unroll
    for (int u = 0; u < 8; ++u) acc[u] = NI;
    int j = 0;
    for (; j + 3 < deg; j += 4) {
        int2 e0 = b[j], e1 = b[j + 1], e2 = b[j + 2], e3 = b[j + 3];
        short8 q0 = *(const short8*)(Qb + (size_t)e0.x * 128 + c0);
        short8 q1 = *(const short8*)(Qb + (size_t)e1.x * 128 + c0);
        short8 q2 = *(const short8*)(Qb + (size_t)e2.x * 128 + c0);
        short8 q3 = *(const short8*)(Qb + (size_t)e3.x * 128 + c0);
        float a0 = __int_as_float(e0.y), a1 = __int_as_float(e1.y);
        float a2 = __int_as_float(e2.y), a3 = __int_as_float(e3.y);
#pragma unroll
        for (int u = 0; u < 8; ++u) {
            acc[u] = fmaxf(acc[u], fmaf(a0, w[u], bf2f((unsigned short)q0[u])));
            acc[u] = fmaxf(acc[u], fmaf(a1, w[u], bf2f((unsigned short)q1[u])));
            acc[u] = fmaxf(acc[u], fmaf(a2, w[u], bf2f((unsigned short)q2[u])));
            acc[u] = fmaxf(acc[u], fmaf(a3, w[u], bf2f((unsigned short)q3[u])));
        }
    }
    for (; j < deg; ++j) {
        int2 e0 = b[j];
        float a0 = __int_as_float(e0.y);
        short8 q0 = *(const short8*)(Qb + (size_t)e0.x * 128 + c0);
#pragma unroll
        for (int u = 0; u < 8; ++u)
            acc[u] = fmaxf(acc[u], fmaf(a0, w[u], bf2f((unsigned short)q0[u])));
    }
    short8 p = *(const short8*)(Pb + (size_t)i * 128 + c0);
    float4 ba = *(const float4*)(bM + c0), bb = *(const float4*)(bM + c0 + 4);
    float bm[8] = {ba.x, ba.y, ba.z, ba.w, bb.x, bb.y, bb.z, bb.w};
    ushort8v o;
#pragma unroll
    for (int u = 0; u < 8; ++u)  // deg==0: -inf -> relu 0 (matches ref)
        o[u] = f2bf(fmaxf(bf2f((unsigned short)p[u]) + bm[u] + acc[u], 0.f));
    *(ushort8v*)(zc + (size_t)i * 256 + 128 + c0) = o;
}

// tau = (hsum/N) . (W_term[0:128] + W_term[128:256]) + b_term
__global__ __launch_bounds__(128) void k_tau(
    const float* __restrict__ hsum, const float* __restrict__ Wt,
    const float* __restrict__ bt, float* __restrict__ tau, int N)
{
    __shared__ float sd[128];
    int t = threadIdx.x;
    float v = hsum[t] * (1.f / (float)N) * (Wt[t] + Wt[128 + t]);
    sd[t] = v;
    __syncthreads();
    for (int s = 64; s > 0; s >>= 1) {
        if (t < s) sd[t] += sd[t + s];
        __syncthreads();
    }
    if (t == 0) tau[0] = sd[0] + bt[0];
}

extern "C" void kernel_launch(void* const* d_in, const int* in_sizes, int n_in,
                              void* d_out, int out_size, void* d_ws, size_t ws_size,
                              hipStream_t stream)
{
    const float* x     = (const float*)d_in[0];
    const float* preh  = (const float*)d_in[1];
    const int*   ei    = (const int*)d_in[2];
    const float* attr  = (const float*)d_in[3];
    const float* Wenc  = (const float*)d_in[4];
    const float* benc  = (const float*)d_in[5];
    const float* WM    = (const float*)d_in[6];
    const float* bM    = (const float*)d_in[7];
    const float* WU    = (const float*)d_in[8];
    const float* bU    = (const float*)d_in[9];
    const float* Wd    = (const float*)d_in[10];
    const float* bd    = (const float*)d_in[11];
    const float* Wterm = (const float*)d_in[12];
    const float* bterm = (const float*)d_in[13];
    int N = in_sizes[0];
    int E = in_sizes[3];

    char* wp = (char*)d_ws;
    unsigned short* zc    = (unsigned short*)wp; wp += (size_t)N * 256 * 2;
    unsigned short* Pb    = (unsigned short*)wp; wp += (size_t)N * 128 * 2;
    unsigned short* Qb    = (unsigned short*)wp; wp += (size_t)N * 128 * 2;
    int2*           bucket= (int2*)wp;           wp += (size_t)N * BCAP * 8;
    int*            cnt   = (int*)wp;            wp += (size_t)N * 4;
    float*          hsum  = (float*)wp;          wp += 128 * 4;
    unsigned short* WencT = (unsigned short*)wp; wp += 128 * 128 * 2;
    unsigned short* WM1T  = (unsigned short*)wp; wp += 128 * 128 * 2;
    unsigned short* WM2T  = (unsigned short*)wp; wp += 128 * 128 * 2;
    unsigned short* WUT   = (unsigned short*)wp; wp += 128 * 256 * 2;

    float* hout = (float*)d_out;
    float* yout = hout + (size_t)N * 128;
    float* tau  = yout + N;

    int nb = (N + 63) / 64;
    // zero cnt + hsum in one shot (contiguous)
    hipMemsetAsync(cnt, 0, ((size_t)N + 128) * sizeof(int), stream);

    k_prepw<<<64, 256, 0, stream>>>(Wenc, WM, WU, WencT, WM1T, WM2T, WUT);
    k_enc<<<nb, 256, 0, stream>>>(x, preh, WencT, Wenc, benc, zc, N);
    k_pq<<<nb, 256, 0, stream>>>(zc, WM1T, WM2T, Pb, Qb, N);
    k_scatter<<<(E + 255) / 256, 256, 0, stream>>>(ei, attr, cnt, bucket, E);
    k_agg<<<(N * 16 + 255) / 256, 256, 0, stream>>>(Pb, Qb, bucket, cnt,
                                                    WM + 256 * 128, bM, zc, N);
    k_h<<<nb, 256, 0, stream>>>(zc, WUT, bU, Wd, bd, hout, yout, hsum, N);
    k_tau<<<1, 128, 0, stream>>>(hsum, Wterm, bterm, tau, N);
}

// Round 5
// 274.127 us; speedup vs baseline: 4.4994x; 1.0586x over previous
//
#include <hip/hip_runtime.h>

#define DEVINL __device__ __forceinline__
#define BCAP 64   // bucket capacity per node; deg~Poisson(12.8), P(>64)~3e-23
#define NREP 64   // hsum atomic replicas (contention / 64)

typedef __attribute__((ext_vector_type(8))) short short8;
typedef __attribute__((ext_vector_type(4))) float f32x4;
typedef __attribute__((ext_vector_type(4))) unsigned short ushort4v;
typedef __attribute__((ext_vector_type(8))) unsigned short ushort8v;

DEVINL unsigned short f2bf(float f) {  // RNE float->bf16
    unsigned u = __float_as_uint(f);
    u += 0x7fffu + ((u >> 16) & 1u);
    return (unsigned short)(u >> 16);
}
DEVINL float bf2f(unsigned short s) { return __uint_as_float(((unsigned)s) << 16); }

// Transpose + bf16-convert all weights once. WT[col][k] layouts.
__global__ __launch_bounds__(256) void k_prepw(
    const float* __restrict__ Wenc, const float* __restrict__ WM,
    const float* __restrict__ WU,
    unsigned short* __restrict__ WencT, unsigned short* __restrict__ WM1T,
    unsigned short* __restrict__ WM2T, unsigned short* __restrict__ WUT)
{
    int tid = blockIdx.x * blockDim.x + threadIdx.x;
    int nt = gridDim.x * blockDim.x;
    for (int i = tid; i < 128 * 128; i += nt) {
        int c = i >> 7, k = i & 127;
        WencT[c * 128 + k] = f2bf(Wenc[(1 + k) * 128 + c]);  // rows 1..128
        WM1T[c * 128 + k]  = f2bf(WM[k * 128 + c]);
        WM2T[c * 128 + k]  = f2bf(WM[(128 + k) * 128 + c]);
    }
    for (int i = tid; i < 128 * 256; i += nt) {
        int c = i >> 8, k = i & 255;
        WUT[c * 256 + k] = f2bf(WU[k * 128 + c]);
    }
}

// ---- MFMA GEMM structure: block = 16 nodes, 4 waves SPLIT the 128 output
// cols (wave w -> t8 in {2w, 2w+1} -> cols [32w, 32w+32)). 3125 blocks ->
// 12.5k waves (vs 3128 at the old 64-node tile): latency-hiding, not
// wave-starved. All 4 waves load the same activation row slices (L1 hits).
// D: node = lane&15, col = t8*16 + (lane>>4)*4 + r.

// z = relu([x, pre_h] @ W_enc + b_enc) -> zc[:,0:128] bf16 (row stride 256)
__global__ __launch_bounds__(256) void k_enc(
    const float* __restrict__ x, const float* __restrict__ preh,
    const unsigned short* __restrict__ WencT, const float* __restrict__ Wenc,
    const float* __restrict__ benc, unsigned short* __restrict__ zc, int N)
{
    int t = threadIdx.x;
    int wave = t >> 6, lane = t & 63;
    int m = lane & 15, quad = lane >> 4;
    int node = blockIdx.x * 16 + m;
    bool valid = node < N;
    int nodec = min(node, N - 1);
    f32x4 acc[2] = {(f32x4)0.f, (f32x4)0.f};
    const float* arow = preh + (size_t)nodec * 128;
#pragma unroll
    for (int kc = 0; kc < 4; ++kc) {
        int k0 = kc * 32 + quad * 8;
        float4 f0 = *(const float4*)(arow + k0);
        float4 f1 = *(const float4*)(arow + k0 + 4);
        short8 bfrag;
        bfrag[0] = (short)f2bf(f0.x); bfrag[1] = (short)f2bf(f0.y);
        bfrag[2] = (short)f2bf(f0.z); bfrag[3] = (short)f2bf(f0.w);
        bfrag[4] = (short)f2bf(f1.x); bfrag[5] = (short)f2bf(f1.y);
        bfrag[6] = (short)f2bf(f1.z); bfrag[7] = (short)f2bf(f1.w);
#pragma unroll
        for (int tt = 0; tt < 2; ++tt) {
            int t8 = wave * 2 + tt;
            short8 afrag = *(const short8*)(WencT + (size_t)(t8 * 16 + m) * 128 + k0);
            acc[tt] = __builtin_amdgcn_mfma_f32_16x16x32_bf16(afrag, bfrag, acc[tt], 0, 0, 0);
        }
    }
    if (!valid) return;
    float xv = x[node];
    unsigned short* orow = zc + (size_t)node * 256;
#pragma unroll
    for (int tt = 0; tt < 2; ++tt) {
        int col = (wave * 2 + tt) * 16 + quad * 4;
        float4 w0v = *(const float4*)(Wenc + col);  // row 0 of W_enc = x weights
        float4 bv  = *(const float4*)(benc + col);
        ushort4v o;
        o[0] = f2bf(fmaxf(acc[tt][0] + xv * w0v.x + bv.x, 0.f));
        o[1] = f2bf(fmaxf(acc[tt][1] + xv * w0v.y + bv.y, 0.f));
        o[2] = f2bf(fmaxf(acc[tt][2] + xv * w0v.z + bv.z, 0.f));
        o[3] = f2bf(fmaxf(acc[tt][3] + xv * w0v.w + bv.w, 0.f));
        *(ushort4v*)(orow + col) = o;
    }
}

// P = z@WM1 (blockIdx.y=0) / Q = z@WM2 (blockIdx.y=1), bf16 in/out
__global__ __launch_bounds__(256) void k_pq(
    const unsigned short* __restrict__ zc,
    const unsigned short* __restrict__ WM1T, const unsigned short* __restrict__ WM2T,
    unsigned short* __restrict__ Pb, unsigned short* __restrict__ Qb, int N)
{
    const unsigned short* WT = blockIdx.y ? WM2T : WM1T;
    unsigned short* out = blockIdx.y ? Qb : Pb;
    int t = threadIdx.x;
    int wave = t >> 6, lane = t & 63;
    int m = lane & 15, quad = lane >> 4;
    int node = blockIdx.x * 16 + m;
    bool valid = node < N;
    int nodec = min(node, N - 1);
    f32x4 acc[2] = {(f32x4)0.f, (f32x4)0.f};
    const unsigned short* arow = zc + (size_t)nodec * 256;
#pragma unroll
    for (int kc = 0; kc < 4; ++kc) {
        int k0 = kc * 32 + quad * 8;
        short8 bfrag = *(const short8*)(arow + k0);
#pragma unroll
        for (int tt = 0; tt < 2; ++tt) {
            int t8 = wave * 2 + tt;
            short8 afrag = *(const short8*)(WT + (size_t)(t8 * 16 + m) * 128 + k0);
            acc[tt] = __builtin_amdgcn_mfma_f32_16x16x32_bf16(afrag, bfrag, acc[tt], 0, 0, 0);
        }
    }
    if (!valid) return;
    unsigned short* orow = out + (size_t)node * 128;
#pragma unroll
    for (int tt = 0; tt < 2; ++tt) {
        int col = (wave * 2 + tt) * 16 + quad * 4;
        ushort4v o;
        o[0] = f2bf(acc[tt][0]); o[1] = f2bf(acc[tt][1]);
        o[2] = f2bf(acc[tt][2]); o[3] = f2bf(acc[tt][3]);
        *(ushort4v*)(orow + col) = o;
    }
}

// h = relu([z|agg] @ W_U + b_U) -> fp32 d_out;  FUSED: y, hsum epilogues.
__global__ __launch_bounds__(256) void k_h(
    const unsigned short* __restrict__ zc, const unsigned short* __restrict__ WUT,
    const float* __restrict__ bU, const float* __restrict__ Wd,
    const float* __restrict__ bd, float* __restrict__ h,
    float* __restrict__ y, float* __restrict__ hsumR, int N)
{
    __shared__ float ys[4][16];   // per-wave y partials (per node)
    __shared__ float hsb[128];    // per-block column sums (each wave: its 32)
    int t = threadIdx.x;
    int wave = t >> 6, lane = t & 63;
    int m = lane & 15, quad = lane >> 4;
    int node = blockIdx.x * 16 + m;
    bool valid = node < N;
    int nodec = min(node, N - 1);
    f32x4 acc[2] = {(f32x4)0.f, (f32x4)0.f};
    float py = 0.f;  // y partial: wave 0 adds z-part; all waves add their h-part
    const unsigned short* arow = zc + (size_t)nodec * 256;
#pragma unroll
    for (int kc = 0; kc < 8; ++kc) {
        int k0 = kc * 32 + quad * 8;
        short8 bfrag = *(const short8*)(arow + k0);
        if (wave == 0 && kc < 4) {  // z·Wd[:128] term (each (kc,quad) k-slice once)
            float4 wa = *(const float4*)(Wd + k0);
            float4 wb = *(const float4*)(Wd + k0 + 4);
            py += bf2f((unsigned short)bfrag[0]) * wa.x
                + bf2f((unsigned short)bfrag[1]) * wa.y
                + bf2f((unsigned short)bfrag[2]) * wa.z
                + bf2f((unsigned short)bfrag[3]) * wa.w
                + bf2f((unsigned short)bfrag[4]) * wb.x
                + bf2f((unsigned short)bfrag[5]) * wb.y
                + bf2f((unsigned short)bfrag[6]) * wb.z
                + bf2f((unsigned short)bfrag[7]) * wb.w;
        }
#pragma unroll
        for (int tt = 0; tt < 2; ++tt) {
            int t8 = wave * 2 + tt;
            short8 afrag = *(const short8*)(WUT + (size_t)(t8 * 16 + m) * 256 + k0);
            acc[tt] = __builtin_amdgcn_mfma_f32_16x16x32_bf16(afrag, bfrag, acc[tt], 0, 0, 0);
        }
    }
    const float* Wdh = Wd + 128;
    float* orow = h + (size_t)nodec * 128;
#pragma unroll
    for (int tt = 0; tt < 2; ++tt) {
        int col = (wave * 2 + tt) * 16 + quad * 4;
        float4 bv = *(const float4*)(bU + col);
        float4 o;  // zeroed for invalid nodes so hsum stays exact
        o.x = valid ? fmaxf(acc[tt][0] + bv.x, 0.f) : 0.f;
        o.y = valid ? fmaxf(acc[tt][1] + bv.y, 0.f) : 0.f;
        o.z = valid ? fmaxf(acc[tt][2] + bv.z, 0.f) : 0.f;
        o.w = valid ? fmaxf(acc[tt][3] + bv.w, 0.f) : 0.f;
        if (valid) *(float4*)(orow + col) = o;
        float4 wd = *(const float4*)(Wdh + col);
        py += o.x * wd.x + o.y * wd.y + o.z * wd.z + o.w * wd.w;
        // sum over the 16 m-lanes (same cols, different nodes)
        float4 s = o;
#pragma unroll
        for (int mask = 1; mask <= 8; mask <<= 1) {
            s.x += __shfl_xor(s.x, mask, 64);
            s.y += __shfl_xor(s.y, mask, 64);
            s.z += __shfl_xor(s.z, mask, 64);
            s.w += __shfl_xor(s.w, mask, 64);
        }
        if (m == 0) *(float4*)&hsb[col] = s;  // (t8,quad) slots are disjoint
    }
    // y: sum py over the 4 quad-lanes of this node, stage per-wave partial
    py += __shfl_xor(py, 16, 64);
    py += __shfl_xor(py, 32, 64);
    if (lane < 16) ys[wave][lane] = py;
    __syncthreads();
    if (t < 16 && blockIdx.x * 16 + t < N)
        y[blockIdx.x * 16 + t] = ys[0][t] + ys[1][t] + ys[2][t] + ys[3][t] + bd[0];
    if (t < 128)
        atomicAdd(&hsumR[(blockIdx.x & (NREP - 1)) * 128 + t], hsb[t]);
}

// Bucket scatter: bucket[dst][slot] = (src, attr). 640k atomics on 50k ctrs.
__global__ __launch_bounds__(256) void k_scatter(
    const int* __restrict__ ei, const float* __restrict__ attr,
    int* __restrict__ cnt, int2* __restrict__ bucket, int E)
{
    int e = blockIdx.x * blockDim.x + threadIdx.x;
    if (e >= E) return;
    int src = ei[e];
    int dst = ei[E + e];
    float a = attr[e];
    int slot = atomicAdd(&cnt[dst], 1);
    if (slot < BCAP)
        bucket[(size_t)dst * BCAP + slot] = make_int2(src, __float_as_int(a));
}

// agg[i] = max(0, P[i] + bM + max_e(Q[src_e] + a_e*w3)) -> zc[:,128:256] bf16
// 16 lanes per node, 8 cols/lane (16B bf16 gathers of Q rows), 4-deep MLP.
__global__ __launch_bounds__(256) void k_agg(
    const unsigned short* __restrict__ Pb, const unsigned short* __restrict__ Qb,
    const int2* __restrict__ bucket, const int* __restrict__ cnt,
    const float* __restrict__ w3, const float* __restrict__ bM,
    unsigned short* __restrict__ zc, int N)
{
    int gid = blockIdx.x * blockDim.x + threadIdx.x;
    int i = gid >> 4;
    if (i >= N) return;
    int lane = gid & 15;
    int c0 = lane * 8;
    int deg = min(cnt[i], BCAP);
    const int2* b = bucket + (size_t)i * BCAP;
    float w[8], acc[8];
    {
        float4 wa = *(const float4*)(w3 + c0), wb = *(const float4*)(w3 + c0 + 4);
        w[0] = wa.x; w[1] = wa.y; w[2] = wa.z; w[3] = wa.w;
        w[4] = wb.x; w[5] = wb.y; w[6] = wb.z; w[7] = wb.w;
    }
    const float NI = __uint_as_float(0xff800000u);
#pragma unroll
    for (int u = 0; u < 8; ++u) acc[u] = NI;
    int j = 0;
    for (; j + 3 < deg; j += 4) {
        int2 e0 = b[j], e1 = b[j + 1], e2 = b[j + 2], e3 = b[j + 3];
        short8 q0 = *(const short8*)(Qb + (size_t)e0.x * 128 + c0);
        short8 q1 = *(const short8*)(Qb + (size_t)e1.x * 128 + c0);
        short8 q2 = *(const short8*)(Qb + (size_t)e2.x * 128 + c0);
        short8 q3 = *(const short8*)(Qb + (size_t)e3.x * 128 + c0);
        float a0 = __int_as_float(e0.y), a1 = __int_as_float(e1.y);
        float a2 = __int_as_float(e2.y), a3 = __int_as_float(e3.y);
#pragma unroll
        for (int u = 0; u < 8; ++u) {
            acc[u] = fmaxf(acc[u], fmaf(a0, w[u], bf2f((unsigned short)q0[u])));
            acc[u] = fmaxf(acc[u], fmaf(a1, w[u], bf2f((unsigned short)q1[u])));
            acc[u] = fmaxf(acc[u], fmaf(a2, w[u], bf2f((unsigned short)q2[u])));
            acc[u] = fmaxf(acc[u], fmaf(a3, w[u], bf2f((unsigned short)q3[u])));
        }
    }
    for (; j < deg; ++j) {
        int2 e0 = b[j];
        float a0 = __int_as_float(e0.y);
        short8 q0 = *(const short8*)(Qb + (size_t)e0.x * 128 + c0);
#pragma unroll
        for (int u = 0; u < 8; ++u)
            acc[u] = fmaxf(acc[u], fmaf(a0, w[u], bf2f((unsigned short)q0[u])));
    }
    short8 p = *(const short8*)(Pb + (size_t)i * 128 + c0);
    float4 ba = *(const float4*)(bM + c0), bb = *(const float4*)(bM + c0 + 4);
    float bm[8] = {ba.x, ba.y, ba.z, ba.w, bb.x, bb.y, bb.z, bb.w};
    ushort8v o;
#pragma unroll
    for (int u = 0; u < 8; ++u)  // deg==0: -inf -> relu 0 (matches ref)
        o[u] = f2bf(fmaxf(bf2f((unsigned short)p[u]) + bm[u] + acc[u], 0.f));
    *(ushort8v*)(zc + (size_t)i * 256 + 128 + c0) = o;
}

// tau = (sum_r hsumR[r]/N) . (W_term[0:128] + W_term[128:256]) + b_term
__global__ __launch_bounds__(128) void k_tau(
    const float* __restrict__ hsumR, const float* __restrict__ Wt,
    const float* __restrict__ bt, float* __restrict__ tau, int N)
{
    __shared__ float sd[128];
    int t = threadIdx.x;
    float s = 0.f;
#pragma unroll
    for (int r = 0; r < NREP; ++r) s += hsumR[r * 128 + t];
    float v = s * (1.f / (float)N) * (Wt[t] + Wt[128 + t]);
    sd[t] = v;
    __syncthreads();
    for (int o = 64; o > 0; o >>= 1) {
        if (t < o) sd[t] += sd[t + o];
        __syncthreads();
    }
    if (t == 0) tau[0] = sd[0] + bt[0];
}

extern "C" void kernel_launch(void* const* d_in, const int* in_sizes, int n_in,
                              void* d_out, int out_size, void* d_ws, size_t ws_size,
                              hipStream_t stream)
{
    const float* x     = (const float*)d_in[0];
    const float* preh  = (const float*)d_in[1];
    const int*   ei    = (const int*)d_in[2];
    const float* attr  = (const float*)d_in[3];
    const float* Wenc  = (const float*)d_in[4];
    const float* benc  = (const float*)d_in[5];
    const float* WM    = (const float*)d_in[6];
    const float* bM    = (const float*)d_in[7];
    const float* WU    = (const float*)d_in[8];
    const float* bU    = (const float*)d_in[9];
    const float* Wd    = (const float*)d_in[10];
    const float* bd    = (const float*)d_in[11];
    const float* Wterm = (const float*)d_in[12];
    const float* bterm = (const float*)d_in[13];
    int N = in_sizes[0];
    int E = in_sizes[3];

    char* wp = (char*)d_ws;
    unsigned short* zc    = (unsigned short*)wp; wp += (size_t)N * 256 * 2;
    unsigned short* Pb    = (unsigned short*)wp; wp += (size_t)N * 128 * 2;
    unsigned short* Qb    = (unsigned short*)wp; wp += (size_t)N * 128 * 2;
    int2*           bucket= (int2*)wp;           wp += (size_t)N * BCAP * 8;
    int*            cnt   = (int*)wp;            wp += (size_t)N * 4;
    float*          hsumR = (float*)wp;          wp += NREP * 128 * 4;
    unsigned short* WencT = (unsigned short*)wp; wp += 128 * 128 * 2;
    unsigned short* WM1T  = (unsigned short*)wp; wp += 128 * 128 * 2;
    unsigned short* WM2T  = (unsigned short*)wp; wp += 128 * 128 * 2;
    unsigned short* WUT   = (unsigned short*)wp; wp += 128 * 256 * 2;

    float* hout = (float*)d_out;
    float* yout = hout + (size_t)N * 128;
    float* tau  = yout + N;

    int nb16 = (N + 15) / 16;
    // zero cnt + hsumR in one shot (contiguous)
    hipMemsetAsync(cnt, 0, ((size_t)N + NREP * 128) * sizeof(int), stream);

    k_prepw<<<64, 256, 0, stream>>>(Wenc, WM, WU, WencT, WM1T, WM2T, WUT);
    k_scatter<<<(E + 255) / 256, 256, 0, stream>>>(ei, attr, cnt, bucket, E);
    k_enc<<<nb16, 256, 0, stream>>>(x, preh, WencT, Wenc, benc, zc, N);
    k_pq<<<dim3(nb16, 2), 256, 0, stream>>>(zc, WM1T, WM2T, Pb, Qb, N);
    k_agg<<<(N * 16 + 255) / 256, 256, 0, stream>>>(Pb, Qb, bucket, cnt,
                                                    WM + 256 * 128, bM, zc, N);
    k_h<<<nb16, 256, 0, stream>>>(zc, WUT, bU, Wd, bd, hout, yout, hsumR, N);
    k_tau<<<1, 128, 0, stream>>>(hsumR, Wterm, bterm, tau, N);
}

// Round 6
// 252.177 us; speedup vs baseline: 4.8910x; 1.0870x over previous
//
#include <hip/hip_runtime.h>

#define DEVINL __device__ __forceinline__
#define BCAP 64   // bucket capacity per node; deg~Poisson(12.8), P(>64)~3e-23
#define NREP 64   // hsum atomic replicas (contention / 64)

typedef __attribute__((ext_vector_type(8))) short short8;
typedef __attribute__((ext_vector_type(4))) float f32x4;
typedef __attribute__((ext_vector_type(4))) unsigned short ushort4v;
typedef __attribute__((ext_vector_type(8))) unsigned short ushort8v;

DEVINL unsigned short f2bf(float f) {  // RNE float->bf16
    unsigned u = __float_as_uint(f);
    u += 0x7fffu + ((u >> 16) & 1u);
    return (unsigned short)(u >> 16);
}
DEVINL float bf2f(unsigned short s) { return __uint_as_float(((unsigned)s) << 16); }

// blocks 0..63: transpose + bf16-convert weights (WT[col][k] layouts).
// blocks 64.. : bucket scatter (independent of weights).
__global__ __launch_bounds__(256) void k_prep(
    const float* __restrict__ Wenc, const float* __restrict__ WM,
    const float* __restrict__ WU,
    unsigned short* __restrict__ WencT, unsigned short* __restrict__ WM1T,
    unsigned short* __restrict__ WM2T, unsigned short* __restrict__ WUT,
    const int* __restrict__ ei, const float* __restrict__ attr,
    int* __restrict__ cnt, int2* __restrict__ bucket, int E)
{
    if (blockIdx.x < 64) {
        int tid = blockIdx.x * 256 + threadIdx.x;
        const int nt = 64 * 256;
        for (int i = tid; i < 128 * 128; i += nt) {
            int c = i >> 7, k = i & 127;
            WencT[c * 128 + k] = f2bf(Wenc[(1 + k) * 128 + c]);  // rows 1..128
            WM1T[c * 128 + k]  = f2bf(WM[k * 128 + c]);
            WM2T[c * 128 + k]  = f2bf(WM[(128 + k) * 128 + c]);
        }
        for (int i = tid; i < 128 * 256; i += nt) {
            int c = i >> 8, k = i & 255;
            WUT[c * 256 + k] = f2bf(WU[k * 128 + c]);
        }
    } else {
        int e = (blockIdx.x - 64) * 256 + threadIdx.x;
        if (e >= E) return;
        int src = ei[e];
        int dst = ei[E + e];
        float a = attr[e];
        int slot = atomicAdd(&cnt[dst], 1);
        if (slot < BCAP)
            bucket[(size_t)dst * BCAP + slot] = make_int2(src, __float_as_int(a));
    }
}

// ---- MFMA structure: block = 16 nodes, 4 waves split the 128 output cols
// (wave w -> t8 in {2w,2w+1} -> cols [32w,32w+32)).
// D: node = lane&15, col = t8*16 + (lane>>4)*4 + r.

// Fused: z = relu([x,pre_h]@W_enc+b) -> global zb + LDS;  P = z@WM1, Q = z@WM2.
__global__ __launch_bounds__(256) void k_zpq(
    const float* __restrict__ x, const float* __restrict__ preh,
    const unsigned short* __restrict__ WencT, const float* __restrict__ Wenc,
    const float* __restrict__ benc,
    const unsigned short* __restrict__ WM1T, const unsigned short* __restrict__ WM2T,
    unsigned short* __restrict__ zb, unsigned short* __restrict__ Pb,
    unsigned short* __restrict__ Qb, int N)
{
    __shared__ __align__(16) unsigned short zl[16][136];  // +8 pad: bank spread
    int t = threadIdx.x;
    int wave = t >> 6, lane = t & 63;
    int m = lane & 15, quad = lane >> 4;
    int node = blockIdx.x * 16 + m;
    bool valid = node < N;
    int nodec = min(node, N - 1);
    // ---- phase A: z tile
    f32x4 acc[2] = {(f32x4)0.f, (f32x4)0.f};
    const float* arow = preh + (size_t)nodec * 128;
#pragma unroll
    for (int kc = 0; kc < 4; ++kc) {
        int k0 = kc * 32 + quad * 8;
        float4 f0 = *(const float4*)(arow + k0);
        float4 f1 = *(const float4*)(arow + k0 + 4);
        short8 bfrag;
        bfrag[0] = (short)f2bf(f0.x); bfrag[1] = (short)f2bf(f0.y);
        bfrag[2] = (short)f2bf(f0.z); bfrag[3] = (short)f2bf(f0.w);
        bfrag[4] = (short)f2bf(f1.x); bfrag[5] = (short)f2bf(f1.y);
        bfrag[6] = (short)f2bf(f1.z); bfrag[7] = (short)f2bf(f1.w);
#pragma unroll
        for (int tt = 0; tt < 2; ++tt) {
            int t8 = wave * 2 + tt;
            short8 afrag = *(const short8*)(WencT + (size_t)(t8 * 16 + m) * 128 + k0);
            acc[tt] = __builtin_amdgcn_mfma_f32_16x16x32_bf16(afrag, bfrag, acc[tt], 0, 0, 0);
        }
    }
    float xv = x[nodec];
#pragma unroll
    for (int tt = 0; tt < 2; ++tt) {
        int col = (wave * 2 + tt) * 16 + quad * 4;
        float4 w0v = *(const float4*)(Wenc + col);  // row 0 of W_enc = x weights
        float4 bv  = *(const float4*)(benc + col);
        ushort4v o;
        o[0] = f2bf(fmaxf(acc[tt][0] + xv * w0v.x + bv.x, 0.f));
        o[1] = f2bf(fmaxf(acc[tt][1] + xv * w0v.y + bv.y, 0.f));
        o[2] = f2bf(fmaxf(acc[tt][2] + xv * w0v.z + bv.z, 0.f));
        o[3] = f2bf(fmaxf(acc[tt][3] + xv * w0v.w + bv.w, 0.f));
        if (valid) *(ushort4v*)(zb + (size_t)node * 128 + col) = o;
        *(ushort4v*)&zl[m][col] = o;  // stage for phase B (garbage ok if !valid)
    }
    __syncthreads();
    // ---- phase B: P,Q from LDS z
    f32x4 aP[2] = {(f32x4)0.f, (f32x4)0.f};
    f32x4 aQ[2] = {(f32x4)0.f, (f32x4)0.f};
#pragma unroll
    for (int kc = 0; kc < 4; ++kc) {
        int k0 = kc * 32 + quad * 8;
        short8 bfrag = *(const short8*)&zl[m][k0];
#pragma unroll
        for (int tt = 0; tt < 2; ++tt) {
            int t8 = wave * 2 + tt;
            size_t wo = (size_t)(t8 * 16 + m) * 128 + k0;
            short8 a1 = *(const short8*)(WM1T + wo);
            aP[tt] = __builtin_amdgcn_mfma_f32_16x16x32_bf16(a1, bfrag, aP[tt], 0, 0, 0);
            short8 a2 = *(const short8*)(WM2T + wo);
            aQ[tt] = __builtin_amdgcn_mfma_f32_16x16x32_bf16(a2, bfrag, aQ[tt], 0, 0, 0);
        }
    }
    if (!valid) return;
    unsigned short* prow = Pb + (size_t)node * 128;
    unsigned short* qrow = Qb + (size_t)node * 128;
#pragma unroll
    for (int tt = 0; tt < 2; ++tt) {
        int col = (wave * 2 + tt) * 16 + quad * 4;
        ushort4v op, oq;
        op[0] = f2bf(aP[tt][0]); op[1] = f2bf(aP[tt][1]);
        op[2] = f2bf(aP[tt][2]); op[3] = f2bf(aP[tt][3]);
        oq[0] = f2bf(aQ[tt][0]); oq[1] = f2bf(aQ[tt][1]);
        oq[2] = f2bf(aQ[tt][2]); oq[3] = f2bf(aQ[tt][3]);
        *(ushort4v*)(prow + col) = op;
        *(ushort4v*)(qrow + col) = oq;
    }
}

// Fused: phase A agg gather -> LDS (bf16);  phase B h = relu([z|agg]@W_U+b)
// + y, hsum epilogues.
__global__ __launch_bounds__(256) void k_aggh(
    const unsigned short* __restrict__ zb, const unsigned short* __restrict__ Pb,
    const unsigned short* __restrict__ Qb, const int2* __restrict__ bucket,
    const int* __restrict__ cnt, const float* __restrict__ w3,
    const float* __restrict__ bM, const unsigned short* __restrict__ WUT,
    const float* __restrict__ bU, const float* __restrict__ Wd,
    const float* __restrict__ bd, float* __restrict__ h,
    float* __restrict__ y, float* __restrict__ hsumR, int N)
{
    __shared__ __align__(16) unsigned short al[16][136];  // agg tile, bf16
    __shared__ float ys[4][16];
    __shared__ float hsb[128];
    int t = threadIdx.x;
    // ---- phase A: agg for this block's 16 nodes (16 threads/node, 8 cols ea)
    {
        int il = t >> 4, lane16 = t & 15, c0 = lane16 * 8;
        int i = blockIdx.x * 16 + il;
        int ic = min(i, N - 1);
        int deg = min(cnt[ic], BCAP);
        const int2* b = bucket + (size_t)ic * BCAP;
        float w[8], acc[8];
        {
            float4 wa = *(const float4*)(w3 + c0), wb = *(const float4*)(w3 + c0 + 4);
            w[0] = wa.x; w[1] = wa.y; w[2] = wa.z; w[3] = wa.w;
            w[4] = wb.x; w[5] = wb.y; w[6] = wb.z; w[7] = wb.w;
        }
        const float NI = __uint_as_float(0xff800000u);
#pragma unroll
        for (int u = 0; u < 8; ++u) acc[u] = NI;
        int j = 0;
        for (; j + 3 < deg; j += 4) {
            int2 e0 = b[j], e1 = b[j + 1], e2 = b[j + 2], e3 = b[j + 3];
            short8 q0 = *(const short8*)(Qb + (size_t)e0.x * 128 + c0);
            short8 q1 = *(const short8*)(Qb + (size_t)e1.x * 128 + c0);
            short8 q2 = *(const short8*)(Qb + (size_t)e2.x * 128 + c0);
            short8 q3 = *(const short8*)(Qb + (size_t)e3.x * 128 + c0);
            float a0 = __int_as_float(e0.y), a1 = __int_as_float(e1.y);
            float a2 = __int_as_float(e2.y), a3 = __int_as_float(e3.y);
#pragma unroll
            for (int u = 0; u < 8; ++u) {
                acc[u] = fmaxf(acc[u], fmaf(a0, w[u], bf2f((unsigned short)q0[u])));
                acc[u] = fmaxf(acc[u], fmaf(a1, w[u], bf2f((unsigned short)q1[u])));
                acc[u] = fmaxf(acc[u], fmaf(a2, w[u], bf2f((unsigned short)q2[u])));
                acc[u] = fmaxf(acc[u], fmaf(a3, w[u], bf2f((unsigned short)q3[u])));
            }
        }
        for (; j < deg; ++j) {
            int2 e0 = b[j];
            float a0 = __int_as_float(e0.y);
            short8 q0 = *(const short8*)(Qb + (size_t)e0.x * 128 + c0);
#pragma unroll
            for (int u = 0; u < 8; ++u)
                acc[u] = fmaxf(acc[u], fmaf(a0, w[u], bf2f((unsigned short)q0[u])));
        }
        short8 p = *(const short8*)(Pb + (size_t)ic * 128 + c0);
        float4 ba = *(const float4*)(bM + c0), bb = *(const float4*)(bM + c0 + 4);
        float bm[8] = {ba.x, ba.y, ba.z, ba.w, bb.x, bb.y, bb.z, bb.w};
        ushort8v o;
#pragma unroll
        for (int u = 0; u < 8; ++u)  // deg==0: -inf -> relu 0 (matches ref)
            o[u] = f2bf(fmaxf(bf2f((unsigned short)p[u]) + bm[u] + acc[u], 0.f));
        *(ushort8v*)&al[il][c0] = o;
    }
    __syncthreads();
    // ---- phase B: h GEMM (K=256: z from global, agg from LDS)
    int wave = t >> 6, lane = t & 63;
    int m = lane & 15, quad = lane >> 4;
    int node = blockIdx.x * 16 + m;
    bool valid = node < N;
    int nodec = min(node, N - 1);
    f32x4 acc[2] = {(f32x4)0.f, (f32x4)0.f};
    float py = 0.f;  // y partial: wave 0 adds z-part; all waves add their h-part
    const unsigned short* arow = zb + (size_t)nodec * 128;
#pragma unroll
    for (int kc = 0; kc < 8; ++kc) {
        int k0 = kc * 32 + quad * 8;
        short8 bfrag;
        if (kc < 4) {
            bfrag = *(const short8*)(arow + k0);
            if (wave == 0) {  // z·Wd[:128] term (each (kc,quad) k-slice once)
                float4 wa = *(const float4*)(Wd + k0);
                float4 wb = *(const float4*)(Wd + k0 + 4);
                py += bf2f((unsigned short)bfrag[0]) * wa.x
                    + bf2f((unsigned short)bfrag[1]) * wa.y
                    + bf2f((unsigned short)bfrag[2]) * wa.z
                    + bf2f((unsigned short)bfrag[3]) * wa.w
                    + bf2f((unsigned short)bfrag[4]) * wb.x
                    + bf2f((unsigned short)bfrag[5]) * wb.y
                    + bf2f((unsigned short)bfrag[6]) * wb.z
                    + bf2f((unsigned short)bfrag[7]) * wb.w;
            }
        } else {
            bfrag = *(const short8*)&al[m][(kc - 4) * 32 + quad * 8];
        }
#pragma unroll
        for (int tt = 0; tt < 2; ++tt) {
            int t8 = wave * 2 + tt;
            short8 afrag = *(const short8*)(WUT + (size_t)(t8 * 16 + m) * 256 + k0);
            acc[tt] = __builtin_amdgcn_mfma_f32_16x16x32_bf16(afrag, bfrag, acc[tt], 0, 0, 0);
        }
    }
    const float* Wdh = Wd + 128;
    float* orow = h + (size_t)nodec * 128;
#pragma unroll
    for (int tt = 0; tt < 2; ++tt) {
        int col = (wave * 2 + tt) * 16 + quad * 4;
        float4 bv = *(const float4*)(bU + col);
        float4 o;  // zeroed for invalid nodes so hsum stays exact
        o.x = valid ? fmaxf(acc[tt][0] + bv.x, 0.f) : 0.f;
        o.y = valid ? fmaxf(acc[tt][1] + bv.y, 0.f) : 0.f;
        o.z = valid ? fmaxf(acc[tt][2] + bv.z, 0.f) : 0.f;
        o.w = valid ? fmaxf(acc[tt][3] + bv.w, 0.f) : 0.f;
        if (valid) *(float4*)(orow + col) = o;
        float4 wd = *(const float4*)(Wdh + col);
        py += o.x * wd.x + o.y * wd.y + o.z * wd.z + o.w * wd.w;
        // sum over the 16 m-lanes (same cols, different nodes)
        float4 s = o;
#pragma unroll
        for (int mask = 1; mask <= 8; mask <<= 1) {
            s.x += __shfl_xor(s.x, mask, 64);
            s.y += __shfl_xor(s.y, mask, 64);
            s.z += __shfl_xor(s.z, mask, 64);
            s.w += __shfl_xor(s.w, mask, 64);
        }
        if (m == 0) *(float4*)&hsb[col] = s;  // (t8,quad) slots are disjoint
    }
    // y: sum py over the 4 quad-lanes of this node, stage per-wave partial
    py += __shfl_xor(py, 16, 64);
    py += __shfl_xor(py, 32, 64);
    if (lane < 16) ys[wave][lane] = py;
    __syncthreads();
    if (t < 16 && blockIdx.x * 16 + t < N)
        y[blockIdx.x * 16 + t] = ys[0][t] + ys[1][t] + ys[2][t] + ys[3][t] + bd[0];
    if (t < 128)
        atomicAdd(&hsumR[(blockIdx.x & (NREP - 1)) * 128 + t], hsb[t]);
}

// tau = (sum_r hsumR[r]/N) . (W_term[0:128] + W_term[128:256]) + b_term
__global__ __launch_bounds__(128) void k_tau(
    const float* __restrict__ hsumR, const float* __restrict__ Wt,
    const float* __restrict__ bt, float* __restrict__ tau, int N)
{
    __shared__ float sd[128];
    int t = threadIdx.x;
    float s = 0.f;
#pragma unroll
    for (int r = 0; r < NREP; ++r) s += hsumR[r * 128 + t];
    float v = s * (1.f / (float)N) * (Wt[t] + Wt[128 + t]);
    sd[t] = v;
    __syncthreads();
    for (int o = 64; o > 0; o >>= 1) {
        if (t < o) sd[t] += sd[t + o];
        __syncthreads();
    }
    if (t == 0) tau[0] = sd[0] + bt[0];
}

extern "C" void kernel_launch(void* const* d_in, const int* in_sizes, int n_in,
                              void* d_out, int out_size, void* d_ws, size_t ws_size,
                              hipStream_t stream)
{
    const float* x     = (const float*)d_in[0];
    const float* preh  = (const float*)d_in[1];
    const int*   ei    = (const int*)d_in[2];
    const float* attr  = (const float*)d_in[3];
    const float* Wenc  = (const float*)d_in[4];
    const float* benc  = (const float*)d_in[5];
    const float* WM    = (const float*)d_in[6];
    const float* bM    = (const float*)d_in[7];
    const float* WU    = (const float*)d_in[8];
    const float* bU    = (const float*)d_in[9];
    const float* Wd    = (const float*)d_in[10];
    const float* bd    = (const float*)d_in[11];
    const float* Wterm = (const float*)d_in[12];
    const float* bterm = (const float*)d_in[13];
    int N = in_sizes[0];
    int E = in_sizes[3];

    char* wp = (char*)d_ws;
    unsigned short* zb    = (unsigned short*)wp; wp += (size_t)N * 128 * 2;
    unsigned short* Pb    = (unsigned short*)wp; wp += (size_t)N * 128 * 2;
    unsigned short* Qb    = (unsigned short*)wp; wp += (size_t)N * 128 * 2;
    int2*           bucket= (int2*)wp;           wp += (size_t)N * BCAP * 8;
    int*            cnt   = (int*)wp;            wp += (size_t)N * 4;
    float*          hsumR = (float*)wp;          wp += NREP * 128 * 4;
    unsigned short* WencT = (unsigned short*)wp; wp += 128 * 128 * 2;
    unsigned short* WM1T  = (unsigned short*)wp; wp += 128 * 128 * 2;
    unsigned short* WM2T  = (unsigned short*)wp; wp += 128 * 128 * 2;
    unsigned short* WUT   = (unsigned short*)wp; wp += 128 * 256 * 2;

    float* hout = (float*)d_out;
    float* yout = hout + (size_t)N * 128;
    float* tau  = yout + N;

    int nb16 = (N + 15) / 16;
    // zero cnt + hsumR in one shot (contiguous)
    hipMemsetAsync(cnt, 0, ((size_t)N + NREP * 128) * sizeof(int), stream);

    int sb = (E + 255) / 256;
    k_prep<<<64 + sb, 256, 0, stream>>>(Wenc, WM, WU, WencT, WM1T, WM2T, WUT,
                                        ei, attr, cnt, bucket, E);
    k_zpq<<<nb16, 256, 0, stream>>>(x, preh, WencT, Wenc, benc, WM1T, WM2T,
                                    zb, Pb, Qb, N);
    k_aggh<<<nb16, 256, 0, stream>>>(zb, Pb, Qb, bucket, cnt, WM + 256 * 128,
                                     bM, WUT, bU, Wd, bd, hout, yout, hsumR, N);
    k_tau<<<1, 128, 0, stream>>>(hsumR, Wterm, bterm, tau, N);
}